// Round 11
// baseline (490.823 us; speedup 1.0000x reference)
//
#include <hip/hip_runtime.h>
#include <hip/hip_bf16.h>

#define N_NODES 100000
#define N_EDGES 1600000

#define NBKT 782                 // ceil(N_NODES / 128)
#define BKT_CHUNK 13334          // ceil(N_EDGES / 120)
#define SCAT_BLOCKS 120
#define LP 72                    // padded LDS row length in shorts (64 + 8)

#define SORT_BLOCKS 40
#define SORT_CHUNK 2500          // 40 * 2500 = 100000
#define BH2_N (NBKT * SCAT_BLOCKS)   // 93840

typedef __attribute__((ext_vector_type(8))) short short8v;
typedef __attribute__((ext_vector_type(4))) float float4v;
typedef __attribute__((ext_vector_type(4))) unsigned short us4v;
typedef __attribute__((ext_vector_type(2))) unsigned long long ull2v;

__device__ __forceinline__ unsigned short f2bf(float f) {
    unsigned int u = __float_as_uint(f);
    u = (u + 0x7FFFu + ((u >> 16) & 1u)) >> 16;   // RTNE
    return (unsigned short)u;
}
__device__ __forceinline__ float bf2f(unsigned short b) {
    return __uint_as_float((unsigned int)b << 16);
}

// ---------------- CSR build: one histogram pass + big scan + one-pass scatter ----------------

__global__ __launch_bounds__(256) void bkt_hist_kernel(const int* __restrict__ ei, int* __restrict__ bh2) {
    __shared__ int h[NBKT];
    int tid = threadIdx.x;
    for (int i = tid; i < NBKT; i += 256) h[i] = 0;
    __syncthreads();
    int start = blockIdx.x * BKT_CHUNK;
    int end = start + BKT_CHUNK; if (end > N_EDGES) end = N_EDGES;
    for (int i = start + tid; i < end; i += 256) {
        int d = ei[N_EDGES + i];
        atomicAdd(&h[d >> 7], 1);
    }
    __syncthreads();
    for (int i = tid; i < NBKT; i += 256) bh2[i * SCAT_BLOCKS + blockIdx.x] = h[i];
}

__global__ __launch_bounds__(256) void gscan_a_kernel(const int* __restrict__ in, int* __restrict__ bsum, int n) {
    __shared__ int lds[256];
    int tid = threadIdx.x;
    int base = blockIdx.x * 1024 + tid * 4;
    int s = 0;
    #pragma unroll
    for (int i = 0; i < 4; i++) s += (base + i < n) ? in[base + i] : 0;
    lds[tid] = s;
    __syncthreads();
    for (int off = 128; off; off >>= 1) {
        if (tid < off) lds[tid] += lds[tid + off];
        __syncthreads();
    }
    if (tid == 0) bsum[blockIdx.x] = lds[0];
}

// parallel exclusive scan of up to 128 block sums
__global__ __launch_bounds__(128) void scan_b_kernel(int* __restrict__ bsum, int nb) {
    __shared__ int lds[128];
    int tid = threadIdx.x;
    int v = (tid < nb) ? bsum[tid] : 0;
    lds[tid] = v;
    __syncthreads();
    for (int off = 1; off < 128; off <<= 1) {
        int y = 0;
        if (tid >= off) y = lds[tid - off];
        __syncthreads();
        if (tid >= off) lds[tid] += y;
        __syncthreads();
    }
    if (tid < nb) bsum[tid] = lds[tid] - v;   // exclusive
}

__global__ __launch_bounds__(256) void gscan_c_kernel(int* __restrict__ data, const int* __restrict__ bsum, int n) {
    __shared__ int lds[256];
    int tid = threadIdx.x;
    int base = blockIdx.x * 1024 + tid * 4;
    int v[4];
    int s = 0;
    #pragma unroll
    for (int i = 0; i < 4; i++) {
        v[i] = (base + i < n) ? data[base + i] : 0;
        s += v[i];
    }
    lds[tid] = s;
    __syncthreads();
    for (int off = 1; off < 256; off <<= 1) {
        int y = 0;
        if (tid >= off) y = lds[tid - off];
        __syncthreads();
        if (tid >= off) lds[tid] += y;
        __syncthreads();
    }
    int run = bsum[blockIdx.x] + lds[tid] - s;
    #pragma unroll
    for (int i = 0; i < 4; i++) {
        if (base + i < n) data[base + i] = run;
        run += v[i];
    }
}

__global__ __launch_bounds__(256) void extract_off_kernel(const int* __restrict__ bh2, int* __restrict__ bucket_off) {
    int i = blockIdx.x * 256 + threadIdx.x;
    if (i < NBKT) bucket_off[i] = bh2[i * SCAT_BLOCKS];
    if (i == NBKT) bucket_off[NBKT] = N_EDGES;
}

__global__ __launch_bounds__(256) void bkt_scatter2_kernel(const int* __restrict__ ei, const int* __restrict__ bh2,
                                                           int* __restrict__ packed) {
    __shared__ int h[NBKT];
    __shared__ int base[NBKT];
    int tid = threadIdx.x;
    for (int i = tid; i < NBKT; i += 256) { h[i] = 0; base[i] = bh2[i * SCAT_BLOCKS + blockIdx.x]; }
    __syncthreads();
    int start = blockIdx.x * BKT_CHUNK;
    int end = start + BKT_CHUNK; if (end > N_EDGES) end = N_EDGES;
    for (int i = start + tid; i < end; i += 256) {
        int s = ei[i];
        int d = ei[N_EDGES + i];
        int b = d >> 7;
        int pos = base[b] + atomicAdd(&h[b], 1);
        packed[pos] = (s << 7) | (d & 127);
    }
}

__global__ __launch_bounds__(256) void bkt_deg2_kernel(const int* __restrict__ packed, const int* __restrict__ bucket_off,
                                                       int* __restrict__ deg) {
    __shared__ int c[128];
    int tid = threadIdx.x;
    if (tid < 128) c[tid] = 0;
    __syncthreads();
    int s0 = bucket_off[blockIdx.x], s1 = bucket_off[blockIdx.x + 1];
    for (int i = s0 + tid; i < s1; i += 256) atomicAdd(&c[packed[i] & 127], 1);
    __syncthreads();
    int node = blockIdx.x * 128 + tid;
    if (tid < 128 && node < N_NODES) deg[node] = c[tid];
}

__global__ __launch_bounds__(256) void bkt_fill2_kernel(const int* __restrict__ packed, const int* __restrict__ bucket_off,
                                                        const int* __restrict__ row_ptr, const int* __restrict__ rank,
                                                        int* __restrict__ col) {
    __shared__ int rp[128];
    __shared__ int c[128];
    int tid = threadIdx.x;
    int node = blockIdx.x * 128 + tid;
    if (tid < 128) {
        rp[tid] = (node < N_NODES) ? row_ptr[rank[node]] : 0;
        c[tid] = 0;
    }
    __syncthreads();
    int s0 = bucket_off[blockIdx.x], s1 = bucket_off[blockIdx.x + 1];
    for (int i = s0 + tid; i < s1; i += 256) {
        int p = packed[i];
        int dl = p & 127;
        int pos = rp[dl] + atomicAdd(&c[dl], 1);
        col[pos] = rank[p >> 7];
    }
}

// ---------------- degree counting sort (contention-free) ----------------
__global__ __launch_bounds__(256) void dsort_hist_kernel(const int* __restrict__ deg, int* __restrict__ bh) {
    __shared__ int h[64];
    int tid = threadIdx.x;
    if (tid < 64) h[tid] = 0;
    __syncthreads();
    int start = blockIdx.x * SORT_CHUNK;
    int end = start + SORT_CHUNK; if (end > N_NODES) end = N_NODES;
    for (int i = start + tid; i < end; i += 256) atomicAdd(&h[min(deg[i], 63)], 1);
    __syncthreads();
    if (tid < 64) bh[tid * SORT_BLOCKS + blockIdx.x] = h[tid];
}

__global__ __launch_bounds__(256) void dsort_scan_kernel(int* __restrict__ bh) {
    __shared__ int ps[256];
    int tid = threadIdx.x;
    int v[10];
    int s = 0;
    #pragma unroll
    for (int k = 0; k < 10; k++) { v[k] = bh[tid * 10 + k]; s += v[k]; }
    ps[tid] = s;
    __syncthreads();
    for (int off = 1; off < 256; off <<= 1) {
        int y = 0;
        if (tid >= off) y = ps[tid - off];
        __syncthreads();
        if (tid >= off) ps[tid] += y;
        __syncthreads();
    }
    int run = ps[tid] - s;
    #pragma unroll
    for (int k = 0; k < 10; k++) { int t = v[k]; bh[tid * 10 + k] = run; run += t; }
}

__global__ __launch_bounds__(256) void dsort_scat_kernel(const int* __restrict__ deg, const int* __restrict__ bh,
                                                         int* __restrict__ ord, int* __restrict__ rank,
                                                         int* __restrict__ deg_s) {
    __shared__ int h[64];
    __shared__ int base[64];
    int tid = threadIdx.x;
    if (tid < 64) { h[tid] = 0; base[tid] = bh[tid * SORT_BLOCKS + blockIdx.x]; }
    __syncthreads();
    int start = blockIdx.x * SORT_CHUNK;
    int end = start + SORT_CHUNK; if (end > N_NODES) end = N_NODES;
    for (int i = start + tid; i < end; i += 256) {
        int d = deg[i];
        int b = min(d, 63);
        int pos = base[b] + atomicAdd(&h[b], 1);
        ord[pos] = i;
        rank[i] = pos;
        deg_s[pos] = d;
    }
}

// ---------------- scan of deg_s -> row_ptr (sorted space, with sentinel) ----------------
__global__ __launch_bounds__(256) void scan_c_row_kernel(const int* __restrict__ deg, const int* __restrict__ bsum,
                                                         int* __restrict__ row_ptr) {
    __shared__ int lds[256];
    int tid = threadIdx.x;
    int base = blockIdx.x * 1024 + tid * 4;
    int v[4];
    int s = 0;
    #pragma unroll
    for (int i = 0; i < 4; i++) {
        int idx = base + i;
        v[i] = (idx < N_NODES) ? deg[idx] : 0;
        s += v[i];
    }
    lds[tid] = s;
    __syncthreads();
    for (int off = 1; off < 256; off <<= 1) {
        int y = 0;
        if (tid >= off) y = lds[tid - off];
        __syncthreads();
        if (tid >= off) lds[tid] += y;
        __syncthreads();
    }
    int run = bsum[blockIdx.x] + lds[tid] - s;
    #pragma unroll
    for (int i = 0; i < 4; i++) {
        int idx = base + i;
        if (idx < N_NODES) row_ptr[idx] = run;
        run += v[i];
    }
    if (blockIdx.x == 0 && tid == 0) row_ptr[N_NODES] = N_EDGES;
}

// ---------------- x (fp32, orig space) -> xcat[:,0:64] bf16 at rank[node], ld 128 ----------------
__global__ __launch_bounds__(256) void xbf_kernel(const float* __restrict__ x, const int* __restrict__ rank,
                                                  unsigned short* __restrict__ xcat) {
    int idx = blockIdx.x * 256 + threadIdx.x;   // one float4 per thread
    if (idx < N_NODES * 16) {
        int node = idx >> 4;
        int f0 = (idx & 15) * 4;
        int rn = rank[node];
        float4 v = *(const float4*)(x + (size_t)idx * 4);
        us4v o;
        o.x = f2bf(v.x); o.y = f2bf(v.y); o.z = f2bf(v.z); o.w = f2bf(v.w);
        *(us4v*)(xcat + (size_t)rn * 128 + f0) = o;
    }
}

#define ACCV(u) { a0 += bf2f(u.x); a1 += bf2f(u.y); a2 += bf2f(u.z); a3 += bf2f(u.w); }

// ---------------- layer-1 agg: mean of xcat[j,0:64] -> xcat[i,64:128]; 16 lanes/node ----------------
// Tiered 16/8/4/2/1 unroll; NT col loads (stream-once); NT aggx store (consumed streaming).
__global__ __launch_bounds__(256) void agg64_kernel(unsigned short* __restrict__ xcat,
                                                    const int* __restrict__ row_ptr, const int* __restrict__ col) {
    int tid = threadIdx.x;
    int i = blockIdx.x * 16 + (tid >> 4);
    if (i >= N_NODES) return;
    int f0 = (tid & 15) * 4;
    int s = row_ptr[i], e = row_ptr[i + 1];
    float a0 = 0.f, a1 = 0.f, a2 = 0.f, a3 = 0.f;
    int t = s;
    while (t + 15 < e) {
        int jj[16];
        #pragma unroll
        for (int k = 0; k < 16; k++) jj[k] = __builtin_nontemporal_load(col + t + k);
        #pragma unroll
        for (int k = 0; k < 16; k++) {
            us4v u = *(const us4v*)(xcat + (size_t)jj[k] * 128 + f0);
            ACCV(u)
        }
        t += 16;
    }
    if (t + 7 < e) {
        int jj[8];
        #pragma unroll
        for (int k = 0; k < 8; k++) jj[k] = __builtin_nontemporal_load(col + t + k);
        #pragma unroll
        for (int k = 0; k < 8; k++) {
            us4v u = *(const us4v*)(xcat + (size_t)jj[k] * 128 + f0);
            ACCV(u)
        }
        t += 8;
    }
    if (t + 3 < e) {
        int jj[4];
        #pragma unroll
        for (int k = 0; k < 4; k++) jj[k] = __builtin_nontemporal_load(col + t + k);
        #pragma unroll
        for (int k = 0; k < 4; k++) {
            us4v u = *(const us4v*)(xcat + (size_t)jj[k] * 128 + f0);
            ACCV(u)
        }
        t += 4;
    }
    if (t + 1 < e) {
        int j0 = __builtin_nontemporal_load(col + t);
        int j1 = __builtin_nontemporal_load(col + t + 1);
        us4v u0 = *(const us4v*)(xcat + (size_t)j0 * 128 + f0);
        us4v u1 = *(const us4v*)(xcat + (size_t)j1 * 128 + f0);
        ACCV(u0) ACCV(u1)
        t += 2;
    }
    if (t < e) {
        int j0 = __builtin_nontemporal_load(col + t);
        us4v u = *(const us4v*)(xcat + (size_t)j0 * 128 + f0);
        ACCV(u)
    }
    float di = 1.0f / fmaxf((float)(e - s), 1.0f);
    us4v o;
    o.x = f2bf(a0 * di); o.y = f2bf(a1 * di); o.z = f2bf(a2 * di); o.w = f2bf(a3 * di);
    __builtin_nontemporal_store(o, (us4v*)(xcat + (size_t)i * 128 + 64 + f0));
}

// ---------------- layers 2/3 agg: mean of hcat[j,0:128] -> hcat[i,128:256]; 32 lanes/node ----------------
__global__ __launch_bounds__(256) void agg128_kernel(unsigned short* __restrict__ hcat,
                                                     const int* __restrict__ row_ptr, const int* __restrict__ col) {
    int tid = threadIdx.x;
    int i = blockIdx.x * 8 + (tid >> 5);
    if (i >= N_NODES) return;
    int f0 = (tid & 31) * 4;
    int s = row_ptr[i], e = row_ptr[i + 1];
    float a0 = 0.f, a1 = 0.f, a2 = 0.f, a3 = 0.f;
    int t = s;
    while (t + 15 < e) {
        int jj[16];
        #pragma unroll
        for (int k = 0; k < 16; k++) jj[k] = __builtin_nontemporal_load(col + t + k);
        #pragma unroll
        for (int k = 0; k < 16; k++) {
            us4v u = *(const us4v*)(hcat + (size_t)jj[k] * 256 + f0);
            ACCV(u)
        }
        t += 16;
    }
    if (t + 7 < e) {
        int jj[8];
        #pragma unroll
        for (int k = 0; k < 8; k++) jj[k] = __builtin_nontemporal_load(col + t + k);
        #pragma unroll
        for (int k = 0; k < 8; k++) {
            us4v u = *(const us4v*)(hcat + (size_t)jj[k] * 256 + f0);
            ACCV(u)
        }
        t += 8;
    }
    if (t + 3 < e) {
        int jj[4];
        #pragma unroll
        for (int k = 0; k < 4; k++) jj[k] = __builtin_nontemporal_load(col + t + k);
        #pragma unroll
        for (int k = 0; k < 4; k++) {
            us4v u = *(const us4v*)(hcat + (size_t)jj[k] * 256 + f0);
            ACCV(u)
        }
        t += 4;
    }
    if (t + 1 < e) {
        int j0 = __builtin_nontemporal_load(col + t);
        int j1 = __builtin_nontemporal_load(col + t + 1);
        us4v u0 = *(const us4v*)(hcat + (size_t)j0 * 256 + f0);
        us4v u1 = *(const us4v*)(hcat + (size_t)j1 * 256 + f0);
        ACCV(u0) ACCV(u1)
        t += 2;
    }
    if (t < e) {
        int j0 = __builtin_nontemporal_load(col + t);
        us4v u = *(const us4v*)(hcat + (size_t)j0 * 256 + f0);
        ACCV(u)
    }
    float di = 1.0f / fmaxf((float)(e - s), 1.0f);
    us4v o;
    o.x = f2bf(a0 * di); o.y = f2bf(a1 * di); o.z = f2bf(a2 * di); o.w = f2bf(a3 * di);
    __builtin_nontemporal_store(o, (us4v*)(hcat + (size_t)i * 256 + 128 + f0));
}

// ---------------- weight prep (transposed bf16) ----------------
__global__ __launch_bounds__(256) void wprep1_kernel(const float* __restrict__ Wr1, const float* __restrict__ Wl1,
                                                     const float* __restrict__ Wres, unsigned short* __restrict__ Bt) {
    int idx = blockIdx.x * 256 + threadIdx.x;   // n*128 + k
    if (idx >= 256 * 128) return;
    int n = idx >> 7;
    int k = idx & 127;
    float v;
    if (n < 128) v = (k < 64) ? Wr1[k * 128 + n] : Wl1[(k - 64) * 128 + n];
    else         v = (k < 64) ? Wres[k * 128 + (n - 128)] : 0.f;
    Bt[idx] = f2bf(v);
}

__global__ __launch_bounds__(256) void wprep23_kernel(const float* __restrict__ Wl, const float* __restrict__ Wr,
                                                      unsigned short* __restrict__ Bt) {
    int idx = blockIdx.x * 256 + threadIdx.x;   // n*256 + k
    if (idx >= 128 * 256) return;
    int n = idx >> 8;
    int k = idx & 255;
    float v = (k < 128) ? Wr[k * 128 + n] : Wl[(k - 128) * 128 + n];
    Bt[idx] = f2bf(v);
}

// ---------------- layer-1 fused GEMM+LN ----------------
__global__ __launch_bounds__(256) void mgemm1_ln_kernel(const unsigned short* __restrict__ A,
                                                        const unsigned short* __restrict__ Bt, int M,
                                                        const float* __restrict__ b1, const float* __restrict__ ln_g,
                                                        const float* __restrict__ ln_b, const float* __restrict__ bres,
                                                        unsigned short* __restrict__ hcat) {
    __shared__ unsigned short As[128 * LP];
    __shared__ unsigned short Bs[256 * LP];
    __shared__ float lsum[2][128], lsq[2][128];
    int tid = threadIdx.x;
    int m0 = blockIdx.x * 128;

    int lane = tid & 63;
    int wave = tid >> 6;
    int wm = (wave & 1) * 64;
    int wn = (wave >> 1) * 64;
    int lm = lane & 15;
    int lk = (lane >> 4) * 8;

    float4v accT[4][4], accR[4][4];
    #pragma unroll
    for (int i = 0; i < 4; i++)
        #pragma unroll
        for (int j = 0; j < 4; j++) { accT[i][j] = (float4v)0.f; accR[i][j] = (float4v)0.f; }

    int sr = tid >> 3;
    int sc = (tid & 7) * 8;

    for (int ks = 0; ks < 128; ks += 64) {
        if (ks) __syncthreads();
        int kk = ks + sc;
        #pragma unroll
        for (int rr = 0; rr < 384; rr += 32) {
            int r = sr + rr;
            if (r < 128) {
                int gm = m0 + r; if (gm > M - 1) gm = M - 1;
                ull2v va = __builtin_nontemporal_load((const ull2v*)(A + (size_t)gm * 128 + kk));
                *(ull2v*)&As[r * LP + sc] = va;
            } else {
                int br = r - 128;
                *(ull2v*)&Bs[br * LP + sc] = *(const ull2v*)(Bt + (size_t)br * 128 + kk);
            }
        }
        __syncthreads();

        #pragma unroll
        for (int k0 = 0; k0 < 64; k0 += 32) {
            short8v af[4], bfT[4], bfR[4];
            #pragma unroll
            for (int i = 0; i < 4; i++)
                af[i] = *(const short8v*)&As[(wm + i * 16 + lm) * LP + k0 + lk];
            #pragma unroll
            for (int j = 0; j < 4; j++) {
                bfT[j] = *(const short8v*)&Bs[(wn + j * 16 + lm) * LP + k0 + lk];
                bfR[j] = *(const short8v*)&Bs[(128 + wn + j * 16 + lm) * LP + k0 + lk];
            }
            #pragma unroll
            for (int i = 0; i < 4; i++)
                #pragma unroll
                for (int j = 0; j < 4; j++) {
                    accT[i][j] = __builtin_amdgcn_mfma_f32_16x16x32_bf16(af[i], bfT[j], accT[i][j], 0, 0, 0);
                    accR[i][j] = __builtin_amdgcn_mfma_f32_16x16x32_bf16(af[i], bfR[j], accR[i][j], 0, 0, 0);
                }
        }
    }

    int q = lane >> 4;
    int wnidx = wave >> 1;
    float b1v[4], gv[4], bbv[4], brv[4];
    #pragma unroll
    for (int j = 0; j < 4; j++) {
        int cc = wn + j * 16 + lm;
        b1v[j] = b1[cc]; gv[j] = ln_g[cc]; bbv[j] = ln_b[cc]; brv[j] = bres[cc];
    }
    #pragma unroll
    for (int i = 0; i < 4; i++) {
        #pragma unroll
        for (int r = 0; r < 4; r++) {
            float sp = 0.f, sq = 0.f;
            #pragma unroll
            for (int j = 0; j < 4; j++) {
                float tv = accT[i][j][r] + b1v[j];
                sp += tv; sq += tv * tv;
            }
            #pragma unroll
            for (int off = 1; off < 16; off <<= 1) {
                sp += __shfl_xor(sp, off);
                sq += __shfl_xor(sq, off);
            }
            if (lm == 0) {
                int m = wm + i * 16 + q * 4 + r;
                lsum[wnidx][m] = sp;
                lsq[wnidx][m] = sq;
            }
        }
    }
    __syncthreads();
    #pragma unroll
    for (int i = 0; i < 4; i++) {
        #pragma unroll
        for (int r = 0; r < 4; r++) {
            int m = wm + i * 16 + q * 4 + r;
            float sum = lsum[0][m] + lsum[1][m];
            float s2 = lsq[0][m] + lsq[1][m];
            float mu = sum * (1.f / 128.f);
            float var = s2 * (1.f / 128.f) - mu * mu;
            float rstd = rsqrtf(var + 1e-5f);
            int gm = m0 + m;
            if (gm < M) {
                #pragma unroll
                for (int j = 0; j < 4; j++) {
                    float tv = accT[i][j][r] + b1v[j];
                    float y = fmaxf((tv - mu) * rstd * gv[j] + bbv[j], 0.f) + accR[i][j][r] + brv[j];
                    hcat[(size_t)gm * 256 + wn + j * 16 + lm] = f2bf(y);
                }
            }
        }
    }
}

// ---------------- MFMA bf16 GEMM (layer 2): hcat[:,0:128] = relu(hcat@Bt^T + bias) ----------------
__global__ __launch_bounds__(256) void mgemm_kernel(const unsigned short* __restrict__ A, int lda,
                                                    const unsigned short* __restrict__ Bt, int M,
                                                    const float* __restrict__ bias,
                                                    unsigned short* __restrict__ C, int ldc) {
    __shared__ unsigned short As[128 * LP];
    __shared__ unsigned short Bs[128 * LP];
    int tid = threadIdx.x;
    int m0 = blockIdx.x * 128;
    int n0 = blockIdx.y * 128;

    int lane = tid & 63;
    int wave = tid >> 6;
    int wm = (wave & 1) * 64;
    int wn = (wave >> 1) * 64;
    int lm = lane & 15;
    int lk = (lane >> 4) * 8;

    float4v acc[4][4];
    #pragma unroll
    for (int i = 0; i < 4; i++)
        #pragma unroll
        for (int j = 0; j < 4; j++) acc[i][j] = (float4v)0.f;

    int sr = tid >> 3;
    int sc = (tid & 7) * 8;

    for (int ks = 0; ks < lda; ks += 64) {
        if (ks) __syncthreads();
        int kk = ks + sc;
        #pragma unroll
        for (int rr = 0; rr < 128; rr += 32) {
            int r = sr + rr;
            int gm = m0 + r; if (gm > M - 1) gm = M - 1;
            ull2v va = __builtin_nontemporal_load((const ull2v*)(A + (size_t)gm * lda + kk));
            *(ull2v*)&As[r * LP + sc] = va;
            *(ull2v*)&Bs[r * LP + sc] = *(const ull2v*)(Bt + (size_t)(n0 + r) * lda + kk);
        }
        __syncthreads();

        #pragma unroll
        for (int k0 = 0; k0 < 64; k0 += 32) {
            short8v af[4], bf[4];
            #pragma unroll
            for (int i = 0; i < 4; i++)
                af[i] = *(const short8v*)&As[(wm + i * 16 + lm) * LP + k0 + lk];
            #pragma unroll
            for (int j = 0; j < 4; j++)
                bf[j] = *(const short8v*)&Bs[(wn + j * 16 + lm) * LP + k0 + lk];
            #pragma unroll
            for (int i = 0; i < 4; i++)
                #pragma unroll
                for (int j = 0; j < 4; j++)
                    acc[i][j] = __builtin_amdgcn_mfma_f32_16x16x32_bf16(af[i], bf[j], acc[i][j], 0, 0, 0);
        }
    }

    int r0b = (lane >> 4) * 4;
    #pragma unroll
    for (int i = 0; i < 4; i++) {
        #pragma unroll
        for (int j = 0; j < 4; j++) {
            int cc = n0 + wn + j * 16 + lm;
            float bv = (bias != nullptr) ? bias[cc] : 0.f;
            #pragma unroll
            for (int r = 0; r < 4; r++) {
                int m = m0 + wm + i * 16 + r0b + r;
                if (m < M) {
                    float v = acc[i][j][r];
                    if (bias != nullptr) v = fmaxf(v + bv, 0.f);
                    C[(size_t)m * ldc + cc] = f2bf(v);
                }
            }
        }
    }
}

// ---------------- layer-3 fused GEMM+pq ----------------
__global__ __launch_bounds__(256) void mgemm_pq_kernel(const unsigned short* __restrict__ A, int lda,
                                                       const unsigned short* __restrict__ Bt, int M,
                                                       const float* __restrict__ bias,
                                                       const float* __restrict__ Wl4, const float* __restrict__ Wr4,
                                                       const float* __restrict__ b4,
                                                       float* __restrict__ p, float* __restrict__ q) {
    __shared__ unsigned short As[128 * LP];
    __shared__ unsigned short Bs[128 * LP];
    __shared__ float psA[2][128], qsA[2][128];
    int tid = threadIdx.x;
    int m0 = blockIdx.x * 128;

    int lane = tid & 63;
    int wave = tid >> 6;
    int wm = (wave & 1) * 64;
    int wn = (wave >> 1) * 64;
    int lm = lane & 15;
    int lk = (lane >> 4) * 8;

    float4v acc[4][4];
    #pragma unroll
    for (int i = 0; i < 4; i++)
        #pragma unroll
        for (int j = 0; j < 4; j++) acc[i][j] = (float4v)0.f;

    int sr = tid >> 3;
    int sc = (tid & 7) * 8;

    for (int ks = 0; ks < lda; ks += 64) {
        if (ks) __syncthreads();
        int kk = ks + sc;
        #pragma unroll
        for (int rr = 0; rr < 128; rr += 32) {
            int r = sr + rr;
            int gm = m0 + r; if (gm > M - 1) gm = M - 1;
            ull2v va = __builtin_nontemporal_load((const ull2v*)(A + (size_t)gm * lda + kk));
            *(ull2v*)&As[r * LP + sc] = va;
            *(ull2v*)&Bs[r * LP + sc] = *(const ull2v*)(Bt + (size_t)r * lda + kk);
        }
        __syncthreads();

        #pragma unroll
        for (int k0 = 0; k0 < 64; k0 += 32) {
            short8v af[4], bf[4];
            #pragma unroll
            for (int i = 0; i < 4; i++)
                af[i] = *(const short8v*)&As[(wm + i * 16 + lm) * LP + k0 + lk];
            #pragma unroll
            for (int j = 0; j < 4; j++)
                bf[j] = *(const short8v*)&Bs[(wn + j * 16 + lm) * LP + k0 + lk];
            #pragma unroll
            for (int i = 0; i < 4; i++)
                #pragma unroll
                for (int j = 0; j < 4; j++)
                    acc[i][j] = __builtin_amdgcn_mfma_f32_16x16x32_bf16(af[i], bf[j], acc[i][j], 0, 0, 0);
        }
    }

    int qd = lane >> 4;
    int wnidx = wave >> 1;
    float b3v[4], wlv[4], wrv[4];
    #pragma unroll
    for (int j = 0; j < 4; j++) {
        int cc = wn + j * 16 + lm;
        b3v[j] = bias[cc]; wlv[j] = Wl4[cc]; wrv[j] = Wr4[cc];
    }
    #pragma unroll
    for (int i = 0; i < 4; i++) {
        #pragma unroll
        for (int r = 0; r < 4; r++) {
            float pp = 0.f, qq = 0.f;
            #pragma unroll
            for (int j = 0; j < 4; j++) {
                float hv = fmaxf(acc[i][j][r] + b3v[j], 0.f);
                pp += hv * wlv[j]; qq += hv * wrv[j];
            }
            #pragma unroll
            for (int off = 1; off < 16; off <<= 1) {
                pp += __shfl_xor(pp, off);
                qq += __shfl_xor(qq, off);
            }
            if (lm == 0) {
                int m = wm + i * 16 + qd * 4 + r;
                psA[wnidx][m] = pp;
                qsA[wnidx][m] = qq;
            }
        }
    }
    __syncthreads();
    if (wnidx == 0 && lm == 0) {
        float b4v = b4[0];
        #pragma unroll
        for (int i = 0; i < 4; i++) {
            #pragma unroll
            for (int r = 0; r < 4; r++) {
                int m = wm + i * 16 + qd * 4 + r;
                int gm = m0 + m;
                if (gm < M) {
                    p[gm] = psA[0][m] + psA[1][m];
                    q[gm] = qsA[0][m] + qsA[1][m] + b4v;
                }
            }
        }
    }
}

__global__ __launch_bounds__(256) void final_kernel(const float* __restrict__ p, const float* __restrict__ q,
                                                    const int* __restrict__ row_ptr, const int* __restrict__ col,
                                                    const int* __restrict__ ord, float* __restrict__ out) {
    int i = blockIdx.x * 256 + threadIdx.x;   // sorted slot
    if (i >= N_NODES) return;
    int s = row_ptr[i], e = row_ptr[i + 1];
    float acc = 0.f;
    int t = s;
    for (; t + 3 < e; t += 4) {
        int j0 = __builtin_nontemporal_load(col + t);
        int j1 = __builtin_nontemporal_load(col + t + 1);
        int j2 = __builtin_nontemporal_load(col + t + 2);
        int j3 = __builtin_nontemporal_load(col + t + 3);
        acc += p[j0] + p[j1] + p[j2] + p[j3];
    }
    for (; t < e; t++) acc += p[__builtin_nontemporal_load(col + t)];
    float di = 1.0f / fmaxf((float)(e - s), 1.0f);
    out[ord[i]] = acc * di + q[i];
}

// ---------------- launch ----------------

extern "C" void kernel_launch(void* const* d_in, const int* in_sizes, int n_in,
                              void* d_out, int out_size, void* d_ws, size_t ws_size,
                              hipStream_t stream) {
    const float* x    = (const float*)d_in[0];
    const int*   ei   = (const int*)d_in[1];
    const float* Wl1  = (const float*)d_in[2];
    const float* Wr1  = (const float*)d_in[3];
    const float* b1   = (const float*)d_in[4];
    const float* ln_g = (const float*)d_in[5];
    const float* ln_b = (const float*)d_in[6];
    const float* Wres = (const float*)d_in[7];
    const float* bres = (const float*)d_in[8];
    const float* Wl2  = (const float*)d_in[9];
    const float* Wr2  = (const float*)d_in[10];
    const float* b2   = (const float*)d_in[11];
    const float* Wl3  = (const float*)d_in[12];
    const float* Wr3  = (const float*)d_in[13];
    const float* b3   = (const float*)d_in[14];
    const float* Wl4  = (const float*)d_in[15];
    const float* Wr4  = (const float*)d_in[16];
    const float* b4   = (const float*)d_in[17];
    float* out = (float*)d_out;

    char* w = (char*)d_ws;
    size_t off = 0;
    auto alloc = [&](size_t bytes) -> void* {
        off = (off + 255) & ~(size_t)255;
        void* pp = w + off;
        off += bytes;
        return pp;
    };

    int*   deg        = (int*)alloc(N_NODES * 4);
    int*   deg_s      = (int*)alloc(N_NODES * 4);
    int*   row_ptr    = (int*)alloc((N_NODES + 1) * 4);
    int*   bsum       = (int*)alloc(512);
    int*   col        = (int*)alloc(N_EDGES * 4);
    int*   bucket_off = (int*)alloc((NBKT + 1) * 4);
    int*   bh2        = (int*)alloc(BH2_N * 4);
    int*   bh         = (int*)alloc(64 * SORT_BLOCKS * 4);
    int*   ord        = (int*)alloc(N_NODES * 4);
    int*   rank       = (int*)alloc(N_NODES * 4);
    unsigned short* Btw  = (unsigned short*)alloc(128 * 256 * 2);
    unsigned short* xcat = (unsigned short*)alloc((size_t)N_NODES * 128 * 2);  // [x | aggx] bf16
    unsigned short* hcat = (unsigned short*)alloc((size_t)N_NODES * 256 * 2);  // [h | aggh] bf16
    int*   packed  = (int*)alloc((size_t)N_EDGES * 4);   // CSR build scratch
    float* p       = (float*)alloc(N_NODES * 4);
    float* q       = (float*)alloc(N_NODES * 4);
    (void)ws_size; (void)n_in; (void)in_sizes; (void)out_size;

    const int NB = (N_NODES + 255) / 256;
    const int SCB = (N_NODES + 1023) / 1024;            // 98
    const int BHB = (BH2_N + 1023) / 1024;              // 92
    const int MB = (N_NODES + 127) / 128;               // 782

    // --- CSR build: hist -> scan -> scatter(packed) -> deg; degree sort; row_ptr; fill ---
    bkt_hist_kernel<<<SCAT_BLOCKS, 256, 0, stream>>>(ei, bh2);
    gscan_a_kernel<<<BHB, 256, 0, stream>>>(bh2, bsum, BH2_N);
    scan_b_kernel<<<1, 128, 0, stream>>>(bsum, BHB);
    gscan_c_kernel<<<BHB, 256, 0, stream>>>(bh2, bsum, BH2_N);
    extract_off_kernel<<<(NBKT + 256) / 256, 256, 0, stream>>>(bh2, bucket_off);
    bkt_scatter2_kernel<<<SCAT_BLOCKS, 256, 0, stream>>>(ei, bh2, packed);
    bkt_deg2_kernel<<<NBKT, 256, 0, stream>>>(packed, bucket_off, deg);
    dsort_hist_kernel<<<SORT_BLOCKS, 256, 0, stream>>>(deg, bh);
    dsort_scan_kernel<<<1, 256, 0, stream>>>(bh);
    dsort_scat_kernel<<<SORT_BLOCKS, 256, 0, stream>>>(deg, bh, ord, rank, deg_s);
    gscan_a_kernel<<<SCB, 256, 0, stream>>>(deg_s, bsum, N_NODES);
    scan_b_kernel<<<1, 128, 0, stream>>>(bsum, SCB);
    scan_c_row_kernel<<<SCB, 256, 0, stream>>>(deg_s, bsum, row_ptr);
    bkt_fill2_kernel<<<NBKT, 256, 0, stream>>>(packed, bucket_off, row_ptr, rank, col);

    // --- layer 1: xcat = [x | mean-agg(x)]; fused GEMM+LN -> hcat[:,0:128] ---
    xbf_kernel<<<(N_NODES * 16 + 255) / 256, 256, 0, stream>>>(x, rank, xcat);
    agg64_kernel<<<(N_NODES + 15) / 16, 256, 0, stream>>>(xcat, row_ptr, col);
    wprep1_kernel<<<128, 256, 0, stream>>>(Wr1, Wl1, Wres, Btw);
    mgemm1_ln_kernel<<<MB, 256, 0, stream>>>(xcat, Btw, N_NODES, b1, ln_g, ln_b, bres, hcat);

    // --- layer 2: agg(h) -> hcat[:,128:256]; GEMM [h|aggh] -> hcat[:,0:128] (bias+relu) ---
    agg128_kernel<<<(N_NODES + 7) / 8, 256, 0, stream>>>(hcat, row_ptr, col);
    wprep23_kernel<<<128, 256, 0, stream>>>(Wl2, Wr2, Btw);
    mgemm_kernel<<<dim3(MB, 1), 256, 0, stream>>>(hcat, 256, Btw, N_NODES, b2, hcat, 256);

    // --- layer 3: agg(h) -> hcat[:,128:256]; fused GEMM+pq -> p, q (h3 never stored) ---
    agg128_kernel<<<(N_NODES + 7) / 8, 256, 0, stream>>>(hcat, row_ptr, col);
    wprep23_kernel<<<128, 256, 0, stream>>>(Wl3, Wr3, Btw);
    mgemm_pq_kernel<<<MB, 256, 0, stream>>>(hcat, 256, Btw, N_NODES, b3, Wl4, Wr4, b4, p, q);

    // --- final ---
    final_kernel<<<NB, 256, 0, stream>>>(p, q, row_ptr, col, ord, out);
}

// Round 12
// 458.641 us; speedup vs baseline: 1.0702x; 1.0702x over previous
//
#include <hip/hip_runtime.h>
#include <hip/hip_bf16.h>

#define N_NODES 100000
#define N_EDGES 1600000

#define NBKT 782                 // ceil(N_NODES / 128)
#define BKT_CHUNK 13334          // ceil(N_EDGES / 120)
#define SCAT_BLOCKS 120
#define LP 72                    // padded LDS row length in shorts (64 + 8)

#define SORT_BLOCKS 40
#define SORT_CHUNK 2500          // 40 * 2500 = 100000
#define BH2_N (NBKT * SCAT_BLOCKS)   // 93840

typedef __attribute__((ext_vector_type(8))) short short8v;
typedef __attribute__((ext_vector_type(4))) float float4v;

__device__ __forceinline__ unsigned short f2bf(float f) {
    unsigned int u = __float_as_uint(f);
    u = (u + 0x7FFFu + ((u >> 16) & 1u)) >> 16;   // RTNE
    return (unsigned short)u;
}
__device__ __forceinline__ float bf2f(unsigned short b) {
    return __uint_as_float((unsigned int)b << 16);
}

// ---------------- CSR build: one histogram pass + big scan + one-pass scatter ----------------

__global__ __launch_bounds__(256) void bkt_hist_kernel(const int* __restrict__ ei, int* __restrict__ bh2) {
    __shared__ int h[NBKT];
    int tid = threadIdx.x;
    for (int i = tid; i < NBKT; i += 256) h[i] = 0;
    __syncthreads();
    int start = blockIdx.x * BKT_CHUNK;
    int end = start + BKT_CHUNK; if (end > N_EDGES) end = N_EDGES;
    for (int i = start + tid; i < end; i += 256) {
        int d = ei[N_EDGES + i];
        atomicAdd(&h[d >> 7], 1);
    }
    __syncthreads();
    for (int i = tid; i < NBKT; i += 256) bh2[i * SCAT_BLOCKS + blockIdx.x] = h[i];
}

__global__ __launch_bounds__(256) void gscan_a_kernel(const int* __restrict__ in, int* __restrict__ bsum, int n) {
    __shared__ int lds[256];
    int tid = threadIdx.x;
    int base = blockIdx.x * 1024 + tid * 4;
    int s = 0;
    #pragma unroll
    for (int i = 0; i < 4; i++) s += (base + i < n) ? in[base + i] : 0;
    lds[tid] = s;
    __syncthreads();
    for (int off = 128; off; off >>= 1) {
        if (tid < off) lds[tid] += lds[tid + off];
        __syncthreads();
    }
    if (tid == 0) bsum[blockIdx.x] = lds[0];
}

// parallel exclusive scan of up to 128 block sums
__global__ __launch_bounds__(128) void scan_b_kernel(int* __restrict__ bsum, int nb) {
    __shared__ int lds[128];
    int tid = threadIdx.x;
    int v = (tid < nb) ? bsum[tid] : 0;
    lds[tid] = v;
    __syncthreads();
    for (int off = 1; off < 128; off <<= 1) {
        int y = 0;
        if (tid >= off) y = lds[tid - off];
        __syncthreads();
        if (tid >= off) lds[tid] += y;
        __syncthreads();
    }
    if (tid < nb) bsum[tid] = lds[tid] - v;   // exclusive
}

__global__ __launch_bounds__(256) void gscan_c_kernel(int* __restrict__ data, const int* __restrict__ bsum, int n) {
    __shared__ int lds[256];
    int tid = threadIdx.x;
    int base = blockIdx.x * 1024 + tid * 4;
    int v[4];
    int s = 0;
    #pragma unroll
    for (int i = 0; i < 4; i++) {
        v[i] = (base + i < n) ? data[base + i] : 0;
        s += v[i];
    }
    lds[tid] = s;
    __syncthreads();
    for (int off = 1; off < 256; off <<= 1) {
        int y = 0;
        if (tid >= off) y = lds[tid - off];
        __syncthreads();
        if (tid >= off) lds[tid] += y;
        __syncthreads();
    }
    int run = bsum[blockIdx.x] + lds[tid] - s;
    #pragma unroll
    for (int i = 0; i < 4; i++) {
        if (base + i < n) data[base + i] = run;
        run += v[i];
    }
}

__global__ __launch_bounds__(256) void extract_off_kernel(const int* __restrict__ bh2, int* __restrict__ bucket_off) {
    int i = blockIdx.x * 256 + threadIdx.x;
    if (i < NBKT) bucket_off[i] = bh2[i * SCAT_BLOCKS];
    if (i == NBKT) bucket_off[NBKT] = N_EDGES;
}

__global__ __launch_bounds__(256) void bkt_scatter2_kernel(const int* __restrict__ ei, const int* __restrict__ bh2,
                                                           int* __restrict__ packed) {
    __shared__ int h[NBKT];
    __shared__ int base[NBKT];
    int tid = threadIdx.x;
    for (int i = tid; i < NBKT; i += 256) { h[i] = 0; base[i] = bh2[i * SCAT_BLOCKS + blockIdx.x]; }
    __syncthreads();
    int start = blockIdx.x * BKT_CHUNK;
    int end = start + BKT_CHUNK; if (end > N_EDGES) end = N_EDGES;
    for (int i = start + tid; i < end; i += 256) {
        int s = ei[i];
        int d = ei[N_EDGES + i];
        int b = d >> 7;
        int pos = base[b] + atomicAdd(&h[b], 1);
        packed[pos] = (s << 7) | (d & 127);
    }
}

__global__ __launch_bounds__(256) void bkt_deg2_kernel(const int* __restrict__ packed, const int* __restrict__ bucket_off,
                                                       int* __restrict__ deg) {
    __shared__ int c[128];
    int tid = threadIdx.x;
    if (tid < 128) c[tid] = 0;
    __syncthreads();
    int s0 = bucket_off[blockIdx.x], s1 = bucket_off[blockIdx.x + 1];
    for (int i = s0 + tid; i < s1; i += 256) atomicAdd(&c[packed[i] & 127], 1);
    __syncthreads();
    int node = blockIdx.x * 128 + tid;
    if (tid < 128 && node < N_NODES) deg[node] = c[tid];
}

__global__ __launch_bounds__(256) void bkt_fill2_kernel(const int* __restrict__ packed, const int* __restrict__ bucket_off,
                                                        const int* __restrict__ row_ptr, const int* __restrict__ rank,
                                                        int* __restrict__ col) {
    __shared__ int rp[128];
    __shared__ int c[128];
    int tid = threadIdx.x;
    int node = blockIdx.x * 128 + tid;
    if (tid < 128) {
        rp[tid] = (node < N_NODES) ? row_ptr[rank[node]] : 0;
        c[tid] = 0;
    }
    __syncthreads();
    int s0 = bucket_off[blockIdx.x], s1 = bucket_off[blockIdx.x + 1];
    for (int i = s0 + tid; i < s1; i += 256) {
        int p = packed[i];
        int dl = p & 127;
        int pos = rp[dl] + atomicAdd(&c[dl], 1);
        col[pos] = rank[p >> 7];
    }
}

// ---------------- degree counting sort (contention-free) ----------------
__global__ __launch_bounds__(256) void dsort_hist_kernel(const int* __restrict__ deg, int* __restrict__ bh) {
    __shared__ int h[64];
    int tid = threadIdx.x;
    if (tid < 64) h[tid] = 0;
    __syncthreads();
    int start = blockIdx.x * SORT_CHUNK;
    int end = start + SORT_CHUNK; if (end > N_NODES) end = N_NODES;
    for (int i = start + tid; i < end; i += 256) atomicAdd(&h[min(deg[i], 63)], 1);
    __syncthreads();
    if (tid < 64) bh[tid * SORT_BLOCKS + blockIdx.x] = h[tid];
}

__global__ __launch_bounds__(256) void dsort_scan_kernel(int* __restrict__ bh) {
    __shared__ int ps[256];
    int tid = threadIdx.x;
    int v[10];
    int s = 0;
    #pragma unroll
    for (int k = 0; k < 10; k++) { v[k] = bh[tid * 10 + k]; s += v[k]; }
    ps[tid] = s;
    __syncthreads();
    for (int off = 1; off < 256; off <<= 1) {
        int y = 0;
        if (tid >= off) y = ps[tid - off];
        __syncthreads();
        if (tid >= off) ps[tid] += y;
        __syncthreads();
    }
    int run = ps[tid] - s;
    #pragma unroll
    for (int k = 0; k < 10; k++) { int t = v[k]; bh[tid * 10 + k] = run; run += t; }
}

__global__ __launch_bounds__(256) void dsort_scat_kernel(const int* __restrict__ deg, const int* __restrict__ bh,
                                                         int* __restrict__ ord, int* __restrict__ rank,
                                                         int* __restrict__ deg_s) {
    __shared__ int h[64];
    __shared__ int base[64];
    int tid = threadIdx.x;
    if (tid < 64) { h[tid] = 0; base[tid] = bh[tid * SORT_BLOCKS + blockIdx.x]; }
    __syncthreads();
    int start = blockIdx.x * SORT_CHUNK;
    int end = start + SORT_CHUNK; if (end > N_NODES) end = N_NODES;
    for (int i = start + tid; i < end; i += 256) {
        int d = deg[i];
        int b = min(d, 63);
        int pos = base[b] + atomicAdd(&h[b], 1);
        ord[pos] = i;
        rank[i] = pos;
        deg_s[pos] = d;
    }
}

// ---------------- scan of deg_s -> row_ptr (sorted space, with sentinel) ----------------
__global__ __launch_bounds__(256) void scan_c_row_kernel(const int* __restrict__ deg, const int* __restrict__ bsum,
                                                         int* __restrict__ row_ptr) {
    __shared__ int lds[256];
    int tid = threadIdx.x;
    int base = blockIdx.x * 1024 + tid * 4;
    int v[4];
    int s = 0;
    #pragma unroll
    for (int i = 0; i < 4; i++) {
        int idx = base + i;
        v[i] = (idx < N_NODES) ? deg[idx] : 0;
        s += v[i];
    }
    lds[tid] = s;
    __syncthreads();
    for (int off = 1; off < 256; off <<= 1) {
        int y = 0;
        if (tid >= off) y = lds[tid - off];
        __syncthreads();
        if (tid >= off) lds[tid] += y;
        __syncthreads();
    }
    int run = bsum[blockIdx.x] + lds[tid] - s;
    #pragma unroll
    for (int i = 0; i < 4; i++) {
        int idx = base + i;
        if (idx < N_NODES) row_ptr[idx] = run;
        run += v[i];
    }
    if (blockIdx.x == 0 && tid == 0) row_ptr[N_NODES] = N_EDGES;
}

// ---------------- x (fp32, orig space) -> xcat[:,0:64] bf16 at rank[node], ld 128 ----------------
__global__ __launch_bounds__(256) void xbf_kernel(const float* __restrict__ x, const int* __restrict__ rank,
                                                  unsigned short* __restrict__ xcat) {
    int idx = blockIdx.x * 256 + threadIdx.x;   // one float4 per thread
    if (idx < N_NODES * 16) {
        int node = idx >> 4;
        int f0 = (idx & 15) * 4;
        int rn = rank[node];
        float4 v = *(const float4*)(x + (size_t)idx * 4);
        ushort4 o;
        o.x = f2bf(v.x); o.y = f2bf(v.y); o.z = f2bf(v.z); o.w = f2bf(v.w);
        *(ushort4*)(xcat + (size_t)rn * 128 + f0) = o;
    }
}

#define ACC4(u) { a0 += bf2f(u.x); a1 += bf2f(u.y); a2 += bf2f(u.z); a3 += bf2f(u.w); }

// ---------------- layer-1 agg: mean of xcat[j,0:64] -> xcat[i,64:128]; 16 lanes/node ----------------
// Tiered 8/4/2/1 unroll (empirical optimum: R10 vs R11 — deeper unroll costs occupancy).
__global__ __launch_bounds__(256) void agg64_kernel(unsigned short* __restrict__ xcat,
                                                    const int* __restrict__ row_ptr, const int* __restrict__ col) {
    int tid = threadIdx.x;
    int i = blockIdx.x * 16 + (tid >> 4);
    if (i >= N_NODES) return;
    int f0 = (tid & 15) * 4;
    int s = row_ptr[i], e = row_ptr[i + 1];
    float a0 = 0.f, a1 = 0.f, a2 = 0.f, a3 = 0.f;
    int t = s;
    while (t + 7 < e) {
        int j0 = col[t], j1 = col[t + 1], j2 = col[t + 2], j3 = col[t + 3];
        int j4 = col[t + 4], j5 = col[t + 5], j6 = col[t + 6], j7 = col[t + 7];
        ushort4 u0 = *(const ushort4*)(xcat + (size_t)j0 * 128 + f0);
        ushort4 u1 = *(const ushort4*)(xcat + (size_t)j1 * 128 + f0);
        ushort4 u2 = *(const ushort4*)(xcat + (size_t)j2 * 128 + f0);
        ushort4 u3 = *(const ushort4*)(xcat + (size_t)j3 * 128 + f0);
        ushort4 u4 = *(const ushort4*)(xcat + (size_t)j4 * 128 + f0);
        ushort4 u5 = *(const ushort4*)(xcat + (size_t)j5 * 128 + f0);
        ushort4 u6 = *(const ushort4*)(xcat + (size_t)j6 * 128 + f0);
        ushort4 u7 = *(const ushort4*)(xcat + (size_t)j7 * 128 + f0);
        ACC4(u0) ACC4(u1) ACC4(u2) ACC4(u3) ACC4(u4) ACC4(u5) ACC4(u6) ACC4(u7)
        t += 8;
    }
    if (t + 3 < e) {
        int j0 = col[t], j1 = col[t + 1], j2 = col[t + 2], j3 = col[t + 3];
        ushort4 u0 = *(const ushort4*)(xcat + (size_t)j0 * 128 + f0);
        ushort4 u1 = *(const ushort4*)(xcat + (size_t)j1 * 128 + f0);
        ushort4 u2 = *(const ushort4*)(xcat + (size_t)j2 * 128 + f0);
        ushort4 u3 = *(const ushort4*)(xcat + (size_t)j3 * 128 + f0);
        ACC4(u0) ACC4(u1) ACC4(u2) ACC4(u3)
        t += 4;
    }
    if (t + 1 < e) {
        int j0 = col[t], j1 = col[t + 1];
        ushort4 u0 = *(const ushort4*)(xcat + (size_t)j0 * 128 + f0);
        ushort4 u1 = *(const ushort4*)(xcat + (size_t)j1 * 128 + f0);
        ACC4(u0) ACC4(u1)
        t += 2;
    }
    if (t < e) {
        ushort4 u0 = *(const ushort4*)(xcat + (size_t)col[t] * 128 + f0);
        ACC4(u0)
    }
    float di = 1.0f / fmaxf((float)(e - s), 1.0f);
    ushort4 o;
    o.x = f2bf(a0 * di); o.y = f2bf(a1 * di); o.z = f2bf(a2 * di); o.w = f2bf(a3 * di);
    *(ushort4*)(xcat + (size_t)i * 128 + 64 + f0) = o;
}

// ---------------- layers 2/3 agg: mean of hcat[j,0:128] -> hcat[i,128:256]; 32 lanes/node ----------------
__global__ __launch_bounds__(256) void agg128_kernel(unsigned short* __restrict__ hcat,
                                                     const int* __restrict__ row_ptr, const int* __restrict__ col) {
    int tid = threadIdx.x;
    int i = blockIdx.x * 8 + (tid >> 5);
    if (i >= N_NODES) return;
    int f0 = (tid & 31) * 4;
    int s = row_ptr[i], e = row_ptr[i + 1];
    float a0 = 0.f, a1 = 0.f, a2 = 0.f, a3 = 0.f;
    int t = s;
    while (t + 7 < e) {
        int j0 = col[t], j1 = col[t + 1], j2 = col[t + 2], j3 = col[t + 3];
        int j4 = col[t + 4], j5 = col[t + 5], j6 = col[t + 6], j7 = col[t + 7];
        ushort4 u0 = *(const ushort4*)(hcat + (size_t)j0 * 256 + f0);
        ushort4 u1 = *(const ushort4*)(hcat + (size_t)j1 * 256 + f0);
        ushort4 u2 = *(const ushort4*)(hcat + (size_t)j2 * 256 + f0);
        ushort4 u3 = *(const ushort4*)(hcat + (size_t)j3 * 256 + f0);
        ushort4 u4 = *(const ushort4*)(hcat + (size_t)j4 * 256 + f0);
        ushort4 u5 = *(const ushort4*)(hcat + (size_t)j5 * 256 + f0);
        ushort4 u6 = *(const ushort4*)(hcat + (size_t)j6 * 256 + f0);
        ushort4 u7 = *(const ushort4*)(hcat + (size_t)j7 * 256 + f0);
        ACC4(u0) ACC4(u1) ACC4(u2) ACC4(u3) ACC4(u4) ACC4(u5) ACC4(u6) ACC4(u7)
        t += 8;
    }
    if (t + 3 < e) {
        int j0 = col[t], j1 = col[t + 1], j2 = col[t + 2], j3 = col[t + 3];
        ushort4 u0 = *(const ushort4*)(hcat + (size_t)j0 * 256 + f0);
        ushort4 u1 = *(const ushort4*)(hcat + (size_t)j1 * 256 + f0);
        ushort4 u2 = *(const ushort4*)(hcat + (size_t)j2 * 256 + f0);
        ushort4 u3 = *(const ushort4*)(hcat + (size_t)j3 * 256 + f0);
        ACC4(u0) ACC4(u1) ACC4(u2) ACC4(u3)
        t += 4;
    }
    if (t + 1 < e) {
        int j0 = col[t], j1 = col[t + 1];
        ushort4 u0 = *(const ushort4*)(hcat + (size_t)j0 * 256 + f0);
        ushort4 u1 = *(const ushort4*)(hcat + (size_t)j1 * 256 + f0);
        ACC4(u0) ACC4(u1)
        t += 2;
    }
    if (t < e) {
        ushort4 u0 = *(const ushort4*)(hcat + (size_t)col[t] * 256 + f0);
        ACC4(u0)
    }
    float di = 1.0f / fmaxf((float)(e - s), 1.0f);
    ushort4 o;
    o.x = f2bf(a0 * di); o.y = f2bf(a1 * di); o.z = f2bf(a2 * di); o.w = f2bf(a3 * di);
    *(ushort4*)(hcat + (size_t)i * 256 + 128 + f0) = o;
}

// ---------------- weight prep (transposed bf16) ----------------
__global__ __launch_bounds__(256) void wprep1_kernel(const float* __restrict__ Wr1, const float* __restrict__ Wl1,
                                                     const float* __restrict__ Wres, unsigned short* __restrict__ Bt) {
    int idx = blockIdx.x * 256 + threadIdx.x;   // n*128 + k
    if (idx >= 256 * 128) return;
    int n = idx >> 7;
    int k = idx & 127;
    float v;
    if (n < 128) v = (k < 64) ? Wr1[k * 128 + n] : Wl1[(k - 64) * 128 + n];
    else         v = (k < 64) ? Wres[k * 128 + (n - 128)] : 0.f;
    Bt[idx] = f2bf(v);
}

__global__ __launch_bounds__(256) void wprep23_kernel(const float* __restrict__ Wl, const float* __restrict__ Wr,
                                                      unsigned short* __restrict__ Bt) {
    int idx = blockIdx.x * 256 + threadIdx.x;   // n*256 + k
    if (idx >= 128 * 256) return;
    int n = idx >> 8;
    int k = idx & 255;
    float v = (k < 128) ? Wr[k * 128 + n] : Wl[(k - 128) * 128 + n];
    Bt[idx] = f2bf(v);
}

// ---------------- layer-1 fused GEMM+LN ----------------
__global__ __launch_bounds__(256) void mgemm1_ln_kernel(const unsigned short* __restrict__ A,
                                                        const unsigned short* __restrict__ Bt, int M,
                                                        const float* __restrict__ b1, const float* __restrict__ ln_g,
                                                        const float* __restrict__ ln_b, const float* __restrict__ bres,
                                                        unsigned short* __restrict__ hcat) {
    __shared__ unsigned short As[128 * LP];
    __shared__ unsigned short Bs[256 * LP];
    __shared__ float lsum[2][128], lsq[2][128];
    int tid = threadIdx.x;
    int m0 = blockIdx.x * 128;

    int lane = tid & 63;
    int wave = tid >> 6;
    int wm = (wave & 1) * 64;
    int wn = (wave >> 1) * 64;
    int lm = lane & 15;
    int lk = (lane >> 4) * 8;

    float4v accT[4][4], accR[4][4];
    #pragma unroll
    for (int i = 0; i < 4; i++)
        #pragma unroll
        for (int j = 0; j < 4; j++) { accT[i][j] = (float4v)0.f; accR[i][j] = (float4v)0.f; }

    int sr = tid >> 3;
    int sc = (tid & 7) * 8;

    for (int ks = 0; ks < 128; ks += 64) {
        if (ks) __syncthreads();
        int kk = ks + sc;
        #pragma unroll
        for (int rr = 0; rr < 384; rr += 32) {
            int r = sr + rr;
            if (r < 128) {
                int gm = m0 + r; if (gm > M - 1) gm = M - 1;
                *(ulonglong2*)&As[r * LP + sc] = *(const ulonglong2*)(A + (size_t)gm * 128 + kk);
            } else {
                int br = r - 128;
                *(ulonglong2*)&Bs[br * LP + sc] = *(const ulonglong2*)(Bt + (size_t)br * 128 + kk);
            }
        }
        __syncthreads();

        #pragma unroll
        for (int k0 = 0; k0 < 64; k0 += 32) {
            short8v af[4], bfT[4], bfR[4];
            #pragma unroll
            for (int i = 0; i < 4; i++)
                af[i] = *(const short8v*)&As[(wm + i * 16 + lm) * LP + k0 + lk];
            #pragma unroll
            for (int j = 0; j < 4; j++) {
                bfT[j] = *(const short8v*)&Bs[(wn + j * 16 + lm) * LP + k0 + lk];
                bfR[j] = *(const short8v*)&Bs[(128 + wn + j * 16 + lm) * LP + k0 + lk];
            }
            #pragma unroll
            for (int i = 0; i < 4; i++)
                #pragma unroll
                for (int j = 0; j < 4; j++) {
                    accT[i][j] = __builtin_amdgcn_mfma_f32_16x16x32_bf16(af[i], bfT[j], accT[i][j], 0, 0, 0);
                    accR[i][j] = __builtin_amdgcn_mfma_f32_16x16x32_bf16(af[i], bfR[j], accR[i][j], 0, 0, 0);
                }
        }
    }

    int q = lane >> 4;
    int wnidx = wave >> 1;
    float b1v[4], gv[4], bbv[4], brv[4];
    #pragma unroll
    for (int j = 0; j < 4; j++) {
        int cc = wn + j * 16 + lm;
        b1v[j] = b1[cc]; gv[j] = ln_g[cc]; bbv[j] = ln_b[cc]; brv[j] = bres[cc];
    }
    #pragma unroll
    for (int i = 0; i < 4; i++) {
        #pragma unroll
        for (int r = 0; r < 4; r++) {
            float sp = 0.f, sq = 0.f;
            #pragma unroll
            for (int j = 0; j < 4; j++) {
                float tv = accT[i][j][r] + b1v[j];
                sp += tv; sq += tv * tv;
            }
            #pragma unroll
            for (int off = 1; off < 16; off <<= 1) {
                sp += __shfl_xor(sp, off);
                sq += __shfl_xor(sq, off);
            }
            if (lm == 0) {
                int m = wm + i * 16 + q * 4 + r;
                lsum[wnidx][m] = sp;
                lsq[wnidx][m] = sq;
            }
        }
    }
    __syncthreads();
    #pragma unroll
    for (int i = 0; i < 4; i++) {
        #pragma unroll
        for (int r = 0; r < 4; r++) {
            int m = wm + i * 16 + q * 4 + r;
            float sum = lsum[0][m] + lsum[1][m];
            float s2 = lsq[0][m] + lsq[1][m];
            float mu = sum * (1.f / 128.f);
            float var = s2 * (1.f / 128.f) - mu * mu;
            float rstd = rsqrtf(var + 1e-5f);
            int gm = m0 + m;
            if (gm < M) {
                #pragma unroll
                for (int j = 0; j < 4; j++) {
                    float tv = accT[i][j][r] + b1v[j];
                    float y = fmaxf((tv - mu) * rstd * gv[j] + bbv[j], 0.f) + accR[i][j][r] + brv[j];
                    hcat[(size_t)gm * 256 + wn + j * 16 + lm] = f2bf(y);
                }
            }
        }
    }
}

// ---------------- MFMA bf16 GEMM (layer 2): hcat[:,0:128] = relu(hcat@Bt^T + bias) ----------------
__global__ __launch_bounds__(256) void mgemm_kernel(const unsigned short* __restrict__ A, int lda,
                                                    const unsigned short* __restrict__ Bt, int M,
                                                    const float* __restrict__ bias,
                                                    unsigned short* __restrict__ C, int ldc) {
    __shared__ unsigned short As[128 * LP];
    __shared__ unsigned short Bs[128 * LP];
    int tid = threadIdx.x;
    int m0 = blockIdx.x * 128;
    int n0 = blockIdx.y * 128;

    int lane = tid & 63;
    int wave = tid >> 6;
    int wm = (wave & 1) * 64;
    int wn = (wave >> 1) * 64;
    int lm = lane & 15;
    int lk = (lane >> 4) * 8;

    float4v acc[4][4];
    #pragma unroll
    for (int i = 0; i < 4; i++)
        #pragma unroll
        for (int j = 0; j < 4; j++) acc[i][j] = (float4v)0.f;

    int sr = tid >> 3;
    int sc = (tid & 7) * 8;

    for (int ks = 0; ks < lda; ks += 64) {
        if (ks) __syncthreads();
        int kk = ks + sc;
        #pragma unroll
        for (int rr = 0; rr < 128; rr += 32) {
            int r = sr + rr;
            int gm = m0 + r; if (gm > M - 1) gm = M - 1;
            *(ulonglong2*)&As[r * LP + sc] = *(const ulonglong2*)(A + (size_t)gm * lda + kk);
            *(ulonglong2*)&Bs[r * LP + sc] = *(const ulonglong2*)(Bt + (size_t)(n0 + r) * lda + kk);
        }
        __syncthreads();

        #pragma unroll
        for (int k0 = 0; k0 < 64; k0 += 32) {
            short8v af[4], bf[4];
            #pragma unroll
            for (int i = 0; i < 4; i++)
                af[i] = *(const short8v*)&As[(wm + i * 16 + lm) * LP + k0 + lk];
            #pragma unroll
            for (int j = 0; j < 4; j++)
                bf[j] = *(const short8v*)&Bs[(wn + j * 16 + lm) * LP + k0 + lk];
            #pragma unroll
            for (int i = 0; i < 4; i++)
                #pragma unroll
                for (int j = 0; j < 4; j++)
                    acc[i][j] = __builtin_amdgcn_mfma_f32_16x16x32_bf16(af[i], bf[j], acc[i][j], 0, 0, 0);
        }
    }

    int r0b = (lane >> 4) * 4;
    #pragma unroll
    for (int i = 0; i < 4; i++) {
        #pragma unroll
        for (int j = 0; j < 4; j++) {
            int cc = n0 + wn + j * 16 + lm;
            float bv = (bias != nullptr) ? bias[cc] : 0.f;
            #pragma unroll
            for (int r = 0; r < 4; r++) {
                int m = m0 + wm + i * 16 + r0b + r;
                if (m < M) {
                    float v = acc[i][j][r];
                    if (bias != nullptr) v = fmaxf(v + bv, 0.f);
                    C[(size_t)m * ldc + cc] = f2bf(v);
                }
            }
        }
    }
}

// ---------------- layer-3 fused GEMM+pq ----------------
__global__ __launch_bounds__(256) void mgemm_pq_kernel(const unsigned short* __restrict__ A, int lda,
                                                       const unsigned short* __restrict__ Bt, int M,
                                                       const float* __restrict__ bias,
                                                       const float* __restrict__ Wl4, const float* __restrict__ Wr4,
                                                       const float* __restrict__ b4,
                                                       float* __restrict__ p, float* __restrict__ q) {
    __shared__ unsigned short As[128 * LP];
    __shared__ unsigned short Bs[128 * LP];
    __shared__ float psA[2][128], qsA[2][128];
    int tid = threadIdx.x;
    int m0 = blockIdx.x * 128;

    int lane = tid & 63;
    int wave = tid >> 6;
    int wm = (wave & 1) * 64;
    int wn = (wave >> 1) * 64;
    int lm = lane & 15;
    int lk = (lane >> 4) * 8;

    float4v acc[4][4];
    #pragma unroll
    for (int i = 0; i < 4; i++)
        #pragma unroll
        for (int j = 0; j < 4; j++) acc[i][j] = (float4v)0.f;

    int sr = tid >> 3;
    int sc = (tid & 7) * 8;

    for (int ks = 0; ks < lda; ks += 64) {
        if (ks) __syncthreads();
        int kk = ks + sc;
        #pragma unroll
        for (int rr = 0; rr < 128; rr += 32) {
            int r = sr + rr;
            int gm = m0 + r; if (gm > M - 1) gm = M - 1;
            *(ulonglong2*)&As[r * LP + sc] = *(const ulonglong2*)(A + (size_t)gm * lda + kk);
            *(ulonglong2*)&Bs[r * LP + sc] = *(const ulonglong2*)(Bt + (size_t)r * lda + kk);
        }
        __syncthreads();

        #pragma unroll
        for (int k0 = 0; k0 < 64; k0 += 32) {
            short8v af[4], bf[4];
            #pragma unroll
            for (int i = 0; i < 4; i++)
                af[i] = *(const short8v*)&As[(wm + i * 16 + lm) * LP + k0 + lk];
            #pragma unroll
            for (int j = 0; j < 4; j++)
                bf[j] = *(const short8v*)&Bs[(wn + j * 16 + lm) * LP + k0 + lk];
            #pragma unroll
            for (int i = 0; i < 4; i++)
                #pragma unroll
                for (int j = 0; j < 4; j++)
                    acc[i][j] = __builtin_amdgcn_mfma_f32_16x16x32_bf16(af[i], bf[j], acc[i][j], 0, 0, 0);
        }
    }

    int qd = lane >> 4;
    int wnidx = wave >> 1;
    float b3v[4], wlv[4], wrv[4];
    #pragma unroll
    for (int j = 0; j < 4; j++) {
        int cc = wn + j * 16 + lm;
        b3v[j] = bias[cc]; wlv[j] = Wl4[cc]; wrv[j] = Wr4[cc];
    }
    #pragma unroll
    for (int i = 0; i < 4; i++) {
        #pragma unroll
        for (int r = 0; r < 4; r++) {
            float pp = 0.f, qq = 0.f;
            #pragma unroll
            for (int j = 0; j < 4; j++) {
                float hv = fmaxf(acc[i][j][r] + b3v[j], 0.f);
                pp += hv * wlv[j]; qq += hv * wrv[j];
            }
            #pragma unroll
            for (int off = 1; off < 16; off <<= 1) {
                pp += __shfl_xor(pp, off);
                qq += __shfl_xor(qq, off);
            }
            if (lm == 0) {
                int m = wm + i * 16 + qd * 4 + r;
                psA[wnidx][m] = pp;
                qsA[wnidx][m] = qq;
            }
        }
    }
    __syncthreads();
    if (wnidx == 0 && lm == 0) {
        float b4v = b4[0];
        #pragma unroll
        for (int i = 0; i < 4; i++) {
            #pragma unroll
            for (int r = 0; r < 4; r++) {
                int m = wm + i * 16 + qd * 4 + r;
                int gm = m0 + m;
                if (gm < M) {
                    p[gm] = psA[0][m] + psA[1][m];
                    q[gm] = qsA[0][m] + qsA[1][m] + b4v;
                }
            }
        }
    }
}

__global__ __launch_bounds__(256) void final_kernel(const float* __restrict__ p, const float* __restrict__ q,
                                                    const int* __restrict__ row_ptr, const int* __restrict__ col,
                                                    const int* __restrict__ ord, float* __restrict__ out) {
    int i = blockIdx.x * 256 + threadIdx.x;   // sorted slot
    if (i >= N_NODES) return;
    int s = row_ptr[i], e = row_ptr[i + 1];
    float acc = 0.f;
    int t = s;
    for (; t + 3 < e; t += 4)
        acc += p[col[t]] + p[col[t + 1]] + p[col[t + 2]] + p[col[t + 3]];
    for (; t < e; t++) acc += p[col[t]];
    float di = 1.0f / fmaxf((float)(e - s), 1.0f);
    out[ord[i]] = acc * di + q[i];
}

// ---------------- launch ----------------

extern "C" void kernel_launch(void* const* d_in, const int* in_sizes, int n_in,
                              void* d_out, int out_size, void* d_ws, size_t ws_size,
                              hipStream_t stream) {
    const float* x    = (const float*)d_in[0];
    const int*   ei   = (const int*)d_in[1];
    const float* Wl1  = (const float*)d_in[2];
    const float* Wr1  = (const float*)d_in[3];
    const float* b1   = (const float*)d_in[4];
    const float* ln_g = (const float*)d_in[5];
    const float* ln_b = (const float*)d_in[6];
    const float* Wres = (const float*)d_in[7];
    const float* bres = (const float*)d_in[8];
    const float* Wl2  = (const float*)d_in[9];
    const float* Wr2  = (const float*)d_in[10];
    const float* b2   = (const float*)d_in[11];
    const float* Wl3  = (const float*)d_in[12];
    const float* Wr3  = (const float*)d_in[13];
    const float* b3   = (const float*)d_in[14];
    const float* Wl4  = (const float*)d_in[15];
    const float* Wr4  = (const float*)d_in[16];
    const float* b4   = (const float*)d_in[17];
    float* out = (float*)d_out;

    char* w = (char*)d_ws;
    size_t off = 0;
    auto alloc = [&](size_t bytes) -> void* {
        off = (off + 255) & ~(size_t)255;
        void* pp = w + off;
        off += bytes;
        return pp;
    };

    int*   deg        = (int*)alloc(N_NODES * 4);
    int*   deg_s      = (int*)alloc(N_NODES * 4);
    int*   row_ptr    = (int*)alloc((N_NODES + 1) * 4);
    int*   bsum       = (int*)alloc(512);
    int*   col        = (int*)alloc(N_EDGES * 4);
    int*   bucket_off = (int*)alloc((NBKT + 1) * 4);
    int*   bh2        = (int*)alloc(BH2_N * 4);
    int*   bh         = (int*)alloc(64 * SORT_BLOCKS * 4);
    int*   ord        = (int*)alloc(N_NODES * 4);
    int*   rank       = (int*)alloc(N_NODES * 4);
    unsigned short* Btw  = (unsigned short*)alloc(128 * 256 * 2);
    unsigned short* xcat = (unsigned short*)alloc((size_t)N_NODES * 128 * 2);  // [x | aggx] bf16
    unsigned short* hcat = (unsigned short*)alloc((size_t)N_NODES * 256 * 2);  // [h | aggh] bf16
    int*   packed  = (int*)alloc((size_t)N_EDGES * 4);   // CSR build scratch
    float* p       = (float*)alloc(N_NODES * 4);
    float* q       = (float*)alloc(N_NODES * 4);
    (void)ws_size; (void)n_in; (void)in_sizes; (void)out_size;

    const int NB = (N_NODES + 255) / 256;
    const int SCB = (N_NODES + 1023) / 1024;            // 98
    const int BHB = (BH2_N + 1023) / 1024;              // 92
    const int MB = (N_NODES + 127) / 128;               // 782

    // --- CSR build: hist -> scan -> scatter(packed) -> deg; degree sort; row_ptr; fill ---
    bkt_hist_kernel<<<SCAT_BLOCKS, 256, 0, stream>>>(ei, bh2);
    gscan_a_kernel<<<BHB, 256, 0, stream>>>(bh2, bsum, BH2_N);
    scan_b_kernel<<<1, 128, 0, stream>>>(bsum, BHB);
    gscan_c_kernel<<<BHB, 256, 0, stream>>>(bh2, bsum, BH2_N);
    extract_off_kernel<<<(NBKT + 256) / 256, 256, 0, stream>>>(bh2, bucket_off);
    bkt_scatter2_kernel<<<SCAT_BLOCKS, 256, 0, stream>>>(ei, bh2, packed);
    bkt_deg2_kernel<<<NBKT, 256, 0, stream>>>(packed, bucket_off, deg);
    dsort_hist_kernel<<<SORT_BLOCKS, 256, 0, stream>>>(deg, bh);
    dsort_scan_kernel<<<1, 256, 0, stream>>>(bh);
    dsort_scat_kernel<<<SORT_BLOCKS, 256, 0, stream>>>(deg, bh, ord, rank, deg_s);
    gscan_a_kernel<<<SCB, 256, 0, stream>>>(deg_s, bsum, N_NODES);
    scan_b_kernel<<<1, 128, 0, stream>>>(bsum, SCB);
    scan_c_row_kernel<<<SCB, 256, 0, stream>>>(deg_s, bsum, row_ptr);
    bkt_fill2_kernel<<<NBKT, 256, 0, stream>>>(packed, bucket_off, row_ptr, rank, col);

    // --- layer 1: xcat = [x | mean-agg(x)]; fused GEMM+LN -> hcat[:,0:128] ---
    xbf_kernel<<<(N_NODES * 16 + 255) / 256, 256, 0, stream>>>(x, rank, xcat);
    agg64_kernel<<<(N_NODES + 15) / 16, 256, 0, stream>>>(xcat, row_ptr, col);
    wprep1_kernel<<<128, 256, 0, stream>>>(Wr1, Wl1, Wres, Btw);
    mgemm1_ln_kernel<<<MB, 256, 0, stream>>>(xcat, Btw, N_NODES, b1, ln_g, ln_b, bres, hcat);

    // --- layer 2: agg(h) -> hcat[:,128:256]; GEMM [h|aggh] -> hcat[:,0:128] (bias+relu) ---
    agg128_kernel<<<(N_NODES + 7) / 8, 256, 0, stream>>>(hcat, row_ptr, col);
    wprep23_kernel<<<128, 256, 0, stream>>>(Wl2, Wr2, Btw);
    mgemm_kernel<<<dim3(MB, 1), 256, 0, stream>>>(hcat, 256, Btw, N_NODES, b2, hcat, 256);

    // --- layer 3: agg(h) -> hcat[:,128:256]; fused GEMM+pq -> p, q (h3 never stored) ---
    agg128_kernel<<<(N_NODES + 7) / 8, 256, 0, stream>>>(hcat, row_ptr, col);
    wprep23_kernel<<<128, 256, 0, stream>>>(Wl3, Wr3, Btw);
    mgemm_pq_kernel<<<MB, 256, 0, stream>>>(hcat, 256, Btw, N_NODES, b3, Wl4, Wr4, b4, p, q);

    // --- final ---
    final_kernel<<<NB, 256, 0, stream>>>(p, q, row_ptr, col, ord, out);
}

// Round 13
// 449.009 us; speedup vs baseline: 1.0931x; 1.0215x over previous
//
#include <hip/hip_runtime.h>
#include <hip/hip_bf16.h>

#define N_NODES 100000
#define N_EDGES 1600000

#define NBKT 782                 // ceil(N_NODES / 128)
#define BKT_CHUNK 13334          // ceil(N_EDGES / 120)
#define SCAT_BLOCKS 120
#define LP 72                    // padded LDS row length in shorts (64 + 8)

#define SORT_BLOCKS 40
#define SORT_CHUNK 2500          // 40 * 2500 = 100000
#define BH2_N (NBKT * SCAT_BLOCKS)   // 93840

typedef __attribute__((ext_vector_type(8))) short short8v;
typedef __attribute__((ext_vector_type(4))) float float4v;

__device__ __forceinline__ unsigned short f2bf(float f) {
    unsigned int u = __float_as_uint(f);
    u = (u + 0x7FFFu + ((u >> 16) & 1u)) >> 16;   // RTNE
    return (unsigned short)u;
}
__device__ __forceinline__ float bf2f(unsigned short b) {
    return __uint_as_float((unsigned int)b << 16);
}

// ---------------- CSR build (ORIGINAL node space; bucket = dst>>7) ----------------

__global__ __launch_bounds__(256) void bkt_hist_kernel(const int* __restrict__ ei, int* __restrict__ bh2) {
    __shared__ int h[NBKT];
    int tid = threadIdx.x;
    for (int i = tid; i < NBKT; i += 256) h[i] = 0;
    __syncthreads();
    int start = blockIdx.x * BKT_CHUNK;
    int end = start + BKT_CHUNK; if (end > N_EDGES) end = N_EDGES;
    for (int i = start + tid; i < end; i += 256) {
        int d = ei[N_EDGES + i];
        atomicAdd(&h[d >> 7], 1);
    }
    __syncthreads();
    for (int i = tid; i < NBKT; i += 256) bh2[i * SCAT_BLOCKS + blockIdx.x] = h[i];
}

__global__ __launch_bounds__(256) void gscan_a_kernel(const int* __restrict__ in, int* __restrict__ bsum, int n) {
    __shared__ int lds[256];
    int tid = threadIdx.x;
    int base = blockIdx.x * 1024 + tid * 4;
    int s = 0;
    #pragma unroll
    for (int i = 0; i < 4; i++) s += (base + i < n) ? in[base + i] : 0;
    lds[tid] = s;
    __syncthreads();
    for (int off = 128; off; off >>= 1) {
        if (tid < off) lds[tid] += lds[tid + off];
        __syncthreads();
    }
    if (tid == 0) bsum[blockIdx.x] = lds[0];
}

// parallel exclusive scan of up to 128 block sums
__global__ __launch_bounds__(128) void scan_b_kernel(int* __restrict__ bsum, int nb) {
    __shared__ int lds[128];
    int tid = threadIdx.x;
    int v = (tid < nb) ? bsum[tid] : 0;
    lds[tid] = v;
    __syncthreads();
    for (int off = 1; off < 128; off <<= 1) {
        int y = 0;
        if (tid >= off) y = lds[tid - off];
        __syncthreads();
        if (tid >= off) lds[tid] += y;
        __syncthreads();
    }
    if (tid < nb) bsum[tid] = lds[tid] - v;   // exclusive
}

__global__ __launch_bounds__(256) void gscan_c_kernel(int* __restrict__ data, const int* __restrict__ bsum, int n) {
    __shared__ int lds[256];
    int tid = threadIdx.x;
    int base = blockIdx.x * 1024 + tid * 4;
    int v[4];
    int s = 0;
    #pragma unroll
    for (int i = 0; i < 4; i++) {
        v[i] = (base + i < n) ? data[base + i] : 0;
        s += v[i];
    }
    lds[tid] = s;
    __syncthreads();
    for (int off = 1; off < 256; off <<= 1) {
        int y = 0;
        if (tid >= off) y = lds[tid - off];
        __syncthreads();
        if (tid >= off) lds[tid] += y;
        __syncthreads();
    }
    int run = bsum[blockIdx.x] + lds[tid] - s;
    #pragma unroll
    for (int i = 0; i < 4; i++) {
        if (base + i < n) data[base + i] = run;
        run += v[i];
    }
}

__global__ __launch_bounds__(256) void extract_off_kernel(const int* __restrict__ bh2, int* __restrict__ bucket_off) {
    int i = blockIdx.x * 256 + threadIdx.x;
    if (i < NBKT) bucket_off[i] = bh2[i * SCAT_BLOCKS];
    if (i == NBKT) bucket_off[NBKT] = N_EDGES;
}

__global__ __launch_bounds__(256) void bkt_scatter2_kernel(const int* __restrict__ ei, const int* __restrict__ bh2,
                                                           int* __restrict__ packed) {
    __shared__ int h[NBKT];
    __shared__ int base[NBKT];
    int tid = threadIdx.x;
    for (int i = tid; i < NBKT; i += 256) { h[i] = 0; base[i] = bh2[i * SCAT_BLOCKS + blockIdx.x]; }
    __syncthreads();
    int start = blockIdx.x * BKT_CHUNK;
    int end = start + BKT_CHUNK; if (end > N_EDGES) end = N_EDGES;
    for (int i = start + tid; i < end; i += 256) {
        int s = ei[i];
        int d = ei[N_EDGES + i];
        int b = d >> 7;
        int pos = base[b] + atomicAdd(&h[b], 1);
        packed[pos] = (s << 7) | (d & 127);
    }
}

// per-bucket degree count + in-block scan -> deg[] AND row_ptr[] (original space)
__global__ __launch_bounds__(256) void bkt_degrow_kernel(const int* __restrict__ packed, const int* __restrict__ bucket_off,
                                                         int* __restrict__ deg, int* __restrict__ row_ptr) {
    __shared__ int c[128];
    __shared__ int ps[128];
    int tid = threadIdx.x;
    if (tid < 128) c[tid] = 0;
    __syncthreads();
    int s0 = bucket_off[blockIdx.x], s1 = bucket_off[blockIdx.x + 1];
    for (int i = s0 + tid; i < s1; i += 256) atomicAdd(&c[packed[i] & 127], 1);
    __syncthreads();
    if (tid < 128) ps[tid] = c[tid];
    __syncthreads();
    for (int off = 1; off < 128; off <<= 1) {
        int y = 0;
        if (tid >= off && tid < 128) y = ps[tid - off];
        __syncthreads();
        if (tid >= off && tid < 128) ps[tid] += y;
        __syncthreads();
    }
    int node = blockIdx.x * 128 + tid;
    if (tid < 128 && node < N_NODES) {
        deg[node] = c[tid];
        row_ptr[node] = s0 + ps[tid] - c[tid];   // bucket base + exclusive in-bucket prefix
    }
    if (blockIdx.x == 0 && tid == 0) row_ptr[N_NODES] = N_EDGES;
}

// CSR fill in original space: bucket's col window is contiguous (coalescing-friendly)
__global__ __launch_bounds__(256) void bkt_fill3_kernel(const int* __restrict__ packed, const int* __restrict__ bucket_off,
                                                        const int* __restrict__ row_ptr, int* __restrict__ col) {
    __shared__ int rp[128];
    __shared__ int c[128];
    int tid = threadIdx.x;
    int node = blockIdx.x * 128 + tid;
    if (tid < 128) {
        rp[tid] = (node < N_NODES) ? row_ptr[node] : 0;
        c[tid] = 0;
    }
    __syncthreads();
    int s0 = bucket_off[blockIdx.x], s1 = bucket_off[blockIdx.x + 1];
    for (int i = s0 + tid; i < s1; i += 256) {
        int p = packed[i];
        int dl = p & 127;
        int pos = rp[dl] + atomicAdd(&c[dl], 1);
        col[pos] = p >> 7;
    }
}

// ---------------- degree counting sort -> ord[] only (slot -> original node) ----------------
__global__ __launch_bounds__(256) void dsort_hist_kernel(const int* __restrict__ deg, int* __restrict__ bh) {
    __shared__ int h[64];
    int tid = threadIdx.x;
    if (tid < 64) h[tid] = 0;
    __syncthreads();
    int start = blockIdx.x * SORT_CHUNK;
    int end = start + SORT_CHUNK; if (end > N_NODES) end = N_NODES;
    for (int i = start + tid; i < end; i += 256) atomicAdd(&h[min(deg[i], 63)], 1);
    __syncthreads();
    if (tid < 64) bh[tid * SORT_BLOCKS + blockIdx.x] = h[tid];
}

__global__ __launch_bounds__(256) void dsort_scan_kernel(int* __restrict__ bh) {
    __shared__ int ps[256];
    int tid = threadIdx.x;
    int v[10];
    int s = 0;
    #pragma unroll
    for (int k = 0; k < 10; k++) { v[k] = bh[tid * 10 + k]; s += v[k]; }
    ps[tid] = s;
    __syncthreads();
    for (int off = 1; off < 256; off <<= 1) {
        int y = 0;
        if (tid >= off) y = ps[tid - off];
        __syncthreads();
        if (tid >= off) ps[tid] += y;
        __syncthreads();
    }
    int run = ps[tid] - s;
    #pragma unroll
    for (int k = 0; k < 10; k++) { int t = v[k]; bh[tid * 10 + k] = run; run += t; }
}

__global__ __launch_bounds__(256) void dsort_scat_kernel(const int* __restrict__ deg, const int* __restrict__ bh,
                                                         int* __restrict__ ord) {
    __shared__ int h[64];
    __shared__ int base[64];
    int tid = threadIdx.x;
    if (tid < 64) { h[tid] = 0; base[tid] = bh[tid * SORT_BLOCKS + blockIdx.x]; }
    __syncthreads();
    int start = blockIdx.x * SORT_CHUNK;
    int end = start + SORT_CHUNK; if (end > N_NODES) end = N_NODES;
    for (int i = start + tid; i < end; i += 256) {
        int b = min(deg[i], 63);
        int pos = base[b] + atomicAdd(&h[b], 1);
        ord[pos] = i;
    }
}

// ---------------- x (fp32) -> xcat[:,0:64] bf16, pure streaming ----------------
__global__ __launch_bounds__(256) void xbf_kernel(const float* __restrict__ x, unsigned short* __restrict__ xcat) {
    int idx = blockIdx.x * 256 + threadIdx.x;   // one float4 per thread
    if (idx < N_NODES * 16) {
        int node = idx >> 4;
        int f0 = (idx & 15) * 4;
        float4 v = *(const float4*)(x + (size_t)idx * 4);
        ushort4 o;
        o.x = f2bf(v.x); o.y = f2bf(v.y); o.z = f2bf(v.z); o.w = f2bf(v.w);
        *(ushort4*)(xcat + (size_t)node * 128 + f0) = o;
    }
}

#define ACC4(u) { a0 += bf2f(u.x); a1 += bf2f(u.y); a2 += bf2f(u.z); a3 += bf2f(u.w); }

// ---------------- layer-1 agg: mean of xcat[j,0:64] -> xcat[i,64:128]; 16 lanes/node ----------------
// Degree-sorted processing order via ord[] (uniform trips per wave); storage in orig space.
__global__ __launch_bounds__(256) void agg64_kernel(unsigned short* __restrict__ xcat,
                                                    const int* __restrict__ row_ptr, const int* __restrict__ col,
                                                    const int* __restrict__ ord) {
    int tid = threadIdx.x;
    int slot = blockIdx.x * 16 + (tid >> 4);
    if (slot >= N_NODES) return;
    int i = ord[slot];
    int f0 = (tid & 15) * 4;
    int s = row_ptr[i], e = row_ptr[i + 1];
    float a0 = 0.f, a1 = 0.f, a2 = 0.f, a3 = 0.f;
    int t = s;
    while (t + 7 < e) {
        int j0 = col[t], j1 = col[t + 1], j2 = col[t + 2], j3 = col[t + 3];
        int j4 = col[t + 4], j5 = col[t + 5], j6 = col[t + 6], j7 = col[t + 7];
        ushort4 u0 = *(const ushort4*)(xcat + (size_t)j0 * 128 + f0);
        ushort4 u1 = *(const ushort4*)(xcat + (size_t)j1 * 128 + f0);
        ushort4 u2 = *(const ushort4*)(xcat + (size_t)j2 * 128 + f0);
        ushort4 u3 = *(const ushort4*)(xcat + (size_t)j3 * 128 + f0);
        ushort4 u4 = *(const ushort4*)(xcat + (size_t)j4 * 128 + f0);
        ushort4 u5 = *(const ushort4*)(xcat + (size_t)j5 * 128 + f0);
        ushort4 u6 = *(const ushort4*)(xcat + (size_t)j6 * 128 + f0);
        ushort4 u7 = *(const ushort4*)(xcat + (size_t)j7 * 128 + f0);
        ACC4(u0) ACC4(u1) ACC4(u2) ACC4(u3) ACC4(u4) ACC4(u5) ACC4(u6) ACC4(u7)
        t += 8;
    }
    if (t + 3 < e) {
        int j0 = col[t], j1 = col[t + 1], j2 = col[t + 2], j3 = col[t + 3];
        ushort4 u0 = *(const ushort4*)(xcat + (size_t)j0 * 128 + f0);
        ushort4 u1 = *(const ushort4*)(xcat + (size_t)j1 * 128 + f0);
        ushort4 u2 = *(const ushort4*)(xcat + (size_t)j2 * 128 + f0);
        ushort4 u3 = *(const ushort4*)(xcat + (size_t)j3 * 128 + f0);
        ACC4(u0) ACC4(u1) ACC4(u2) ACC4(u3)
        t += 4;
    }
    if (t + 1 < e) {
        int j0 = col[t], j1 = col[t + 1];
        ushort4 u0 = *(const ushort4*)(xcat + (size_t)j0 * 128 + f0);
        ushort4 u1 = *(const ushort4*)(xcat + (size_t)j1 * 128 + f0);
        ACC4(u0) ACC4(u1)
        t += 2;
    }
    if (t < e) {
        ushort4 u0 = *(const ushort4*)(xcat + (size_t)col[t] * 128 + f0);
        ACC4(u0)
    }
    float di = 1.0f / fmaxf((float)(e - s), 1.0f);
    ushort4 o;
    o.x = f2bf(a0 * di); o.y = f2bf(a1 * di); o.z = f2bf(a2 * di); o.w = f2bf(a3 * di);
    *(ushort4*)(xcat + (size_t)i * 128 + 64 + f0) = o;
}

// ---------------- layers 2/3 agg: mean of hcat[j,0:128] -> hcat[i,128:256]; 32 lanes/node ----------------
__global__ __launch_bounds__(256) void agg128_kernel(unsigned short* __restrict__ hcat,
                                                     const int* __restrict__ row_ptr, const int* __restrict__ col,
                                                     const int* __restrict__ ord) {
    int tid = threadIdx.x;
    int slot = blockIdx.x * 8 + (tid >> 5);
    if (slot >= N_NODES) return;
    int i = ord[slot];
    int f0 = (tid & 31) * 4;
    int s = row_ptr[i], e = row_ptr[i + 1];
    float a0 = 0.f, a1 = 0.f, a2 = 0.f, a3 = 0.f;
    int t = s;
    while (t + 7 < e) {
        int j0 = col[t], j1 = col[t + 1], j2 = col[t + 2], j3 = col[t + 3];
        int j4 = col[t + 4], j5 = col[t + 5], j6 = col[t + 6], j7 = col[t + 7];
        ushort4 u0 = *(const ushort4*)(hcat + (size_t)j0 * 256 + f0);
        ushort4 u1 = *(const ushort4*)(hcat + (size_t)j1 * 256 + f0);
        ushort4 u2 = *(const ushort4*)(hcat + (size_t)j2 * 256 + f0);
        ushort4 u3 = *(const ushort4*)(hcat + (size_t)j3 * 256 + f0);
        ushort4 u4 = *(const ushort4*)(hcat + (size_t)j4 * 256 + f0);
        ushort4 u5 = *(const ushort4*)(hcat + (size_t)j5 * 256 + f0);
        ushort4 u6 = *(const ushort4*)(hcat + (size_t)j6 * 256 + f0);
        ushort4 u7 = *(const ushort4*)(hcat + (size_t)j7 * 256 + f0);
        ACC4(u0) ACC4(u1) ACC4(u2) ACC4(u3) ACC4(u4) ACC4(u5) ACC4(u6) ACC4(u7)
        t += 8;
    }
    if (t + 3 < e) {
        int j0 = col[t], j1 = col[t + 1], j2 = col[t + 2], j3 = col[t + 3];
        ushort4 u0 = *(const ushort4*)(hcat + (size_t)j0 * 256 + f0);
        ushort4 u1 = *(const ushort4*)(hcat + (size_t)j1 * 256 + f0);
        ushort4 u2 = *(const ushort4*)(hcat + (size_t)j2 * 256 + f0);
        ushort4 u3 = *(const ushort4*)(hcat + (size_t)j3 * 256 + f0);
        ACC4(u0) ACC4(u1) ACC4(u2) ACC4(u3)
        t += 4;
    }
    if (t + 1 < e) {
        int j0 = col[t], j1 = col[t + 1];
        ushort4 u0 = *(const ushort4*)(hcat + (size_t)j0 * 256 + f0);
        ushort4 u1 = *(const ushort4*)(hcat + (size_t)j1 * 256 + f0);
        ACC4(u0) ACC4(u1)
        t += 2;
    }
    if (t < e) {
        ushort4 u0 = *(const ushort4*)(hcat + (size_t)col[t] * 256 + f0);
        ACC4(u0)
    }
    float di = 1.0f / fmaxf((float)(e - s), 1.0f);
    ushort4 o;
    o.x = f2bf(a0 * di); o.y = f2bf(a1 * di); o.z = f2bf(a2 * di); o.w = f2bf(a3 * di);
    *(ushort4*)(hcat + (size_t)i * 256 + 128 + f0) = o;
}

// ---------------- weight prep (transposed bf16) ----------------
__global__ __launch_bounds__(256) void wprep1_kernel(const float* __restrict__ Wr1, const float* __restrict__ Wl1,
                                                     const float* __restrict__ Wres, unsigned short* __restrict__ Bt) {
    int idx = blockIdx.x * 256 + threadIdx.x;   // n*128 + k
    if (idx >= 256 * 128) return;
    int n = idx >> 7;
    int k = idx & 127;
    float v;
    if (n < 128) v = (k < 64) ? Wr1[k * 128 + n] : Wl1[(k - 64) * 128 + n];
    else         v = (k < 64) ? Wres[k * 128 + (n - 128)] : 0.f;
    Bt[idx] = f2bf(v);
}

__global__ __launch_bounds__(256) void wprep23_kernel(const float* __restrict__ Wl, const float* __restrict__ Wr,
                                                      unsigned short* __restrict__ Bt) {
    int idx = blockIdx.x * 256 + threadIdx.x;   // n*256 + k
    if (idx >= 128 * 256) return;
    int n = idx >> 8;
    int k = idx & 255;
    float v = (k < 128) ? Wr[k * 128 + n] : Wl[(k - 128) * 128 + n];
    Bt[idx] = f2bf(v);
}

// ---------------- layer-1 fused GEMM+LN ----------------
__global__ __launch_bounds__(256) void mgemm1_ln_kernel(const unsigned short* __restrict__ A,
                                                        const unsigned short* __restrict__ Bt, int M,
                                                        const float* __restrict__ b1, const float* __restrict__ ln_g,
                                                        const float* __restrict__ ln_b, const float* __restrict__ bres,
                                                        unsigned short* __restrict__ hcat) {
    __shared__ unsigned short As[128 * LP];
    __shared__ unsigned short Bs[256 * LP];
    __shared__ float lsum[2][128], lsq[2][128];
    int tid = threadIdx.x;
    int m0 = blockIdx.x * 128;

    int lane = tid & 63;
    int wave = tid >> 6;
    int wm = (wave & 1) * 64;
    int wn = (wave >> 1) * 64;
    int lm = lane & 15;
    int lk = (lane >> 4) * 8;

    float4v accT[4][4], accR[4][4];
    #pragma unroll
    for (int i = 0; i < 4; i++)
        #pragma unroll
        for (int j = 0; j < 4; j++) { accT[i][j] = (float4v)0.f; accR[i][j] = (float4v)0.f; }

    int sr = tid >> 3;
    int sc = (tid & 7) * 8;

    for (int ks = 0; ks < 128; ks += 64) {
        if (ks) __syncthreads();
        int kk = ks + sc;
        #pragma unroll
        for (int rr = 0; rr < 384; rr += 32) {
            int r = sr + rr;
            if (r < 128) {
                int gm = m0 + r; if (gm > M - 1) gm = M - 1;
                *(ulonglong2*)&As[r * LP + sc] = *(const ulonglong2*)(A + (size_t)gm * 128 + kk);
            } else {
                int br = r - 128;
                *(ulonglong2*)&Bs[br * LP + sc] = *(const ulonglong2*)(Bt + (size_t)br * 128 + kk);
            }
        }
        __syncthreads();

        #pragma unroll
        for (int k0 = 0; k0 < 64; k0 += 32) {
            short8v af[4], bfT[4], bfR[4];
            #pragma unroll
            for (int i = 0; i < 4; i++)
                af[i] = *(const short8v*)&As[(wm + i * 16 + lm) * LP + k0 + lk];
            #pragma unroll
            for (int j = 0; j < 4; j++) {
                bfT[j] = *(const short8v*)&Bs[(wn + j * 16 + lm) * LP + k0 + lk];
                bfR[j] = *(const short8v*)&Bs[(128 + wn + j * 16 + lm) * LP + k0 + lk];
            }
            #pragma unroll
            for (int i = 0; i < 4; i++)
                #pragma unroll
                for (int j = 0; j < 4; j++) {
                    accT[i][j] = __builtin_amdgcn_mfma_f32_16x16x32_bf16(af[i], bfT[j], accT[i][j], 0, 0, 0);
                    accR[i][j] = __builtin_amdgcn_mfma_f32_16x16x32_bf16(af[i], bfR[j], accR[i][j], 0, 0, 0);
                }
        }
    }

    int q = lane >> 4;
    int wnidx = wave >> 1;
    float b1v[4], gv[4], bbv[4], brv[4];
    #pragma unroll
    for (int j = 0; j < 4; j++) {
        int cc = wn + j * 16 + lm;
        b1v[j] = b1[cc]; gv[j] = ln_g[cc]; bbv[j] = ln_b[cc]; brv[j] = bres[cc];
    }
    #pragma unroll
    for (int i = 0; i < 4; i++) {
        #pragma unroll
        for (int r = 0; r < 4; r++) {
            float sp = 0.f, sq = 0.f;
            #pragma unroll
            for (int j = 0; j < 4; j++) {
                float tv = accT[i][j][r] + b1v[j];
                sp += tv; sq += tv * tv;
            }
            #pragma unroll
            for (int off = 1; off < 16; off <<= 1) {
                sp += __shfl_xor(sp, off);
                sq += __shfl_xor(sq, off);
            }
            if (lm == 0) {
                int m = wm + i * 16 + q * 4 + r;
                lsum[wnidx][m] = sp;
                lsq[wnidx][m] = sq;
            }
        }
    }
    __syncthreads();
    #pragma unroll
    for (int i = 0; i < 4; i++) {
        #pragma unroll
        for (int r = 0; r < 4; r++) {
            int m = wm + i * 16 + q * 4 + r;
            float sum = lsum[0][m] + lsum[1][m];
            float s2 = lsq[0][m] + lsq[1][m];
            float mu = sum * (1.f / 128.f);
            float var = s2 * (1.f / 128.f) - mu * mu;
            float rstd = rsqrtf(var + 1e-5f);
            int gm = m0 + m;
            if (gm < M) {
                #pragma unroll
                for (int j = 0; j < 4; j++) {
                    float tv = accT[i][j][r] + b1v[j];
                    float y = fmaxf((tv - mu) * rstd * gv[j] + bbv[j], 0.f) + accR[i][j][r] + brv[j];
                    hcat[(size_t)gm * 256 + wn + j * 16 + lm] = f2bf(y);
                }
            }
        }
    }
}

// ---------------- MFMA bf16 GEMM (layer 2): hcat[:,0:128] = relu(hcat@Bt^T + bias) ----------------
__global__ __launch_bounds__(256) void mgemm_kernel(const unsigned short* __restrict__ A, int lda,
                                                    const unsigned short* __restrict__ Bt, int M,
                                                    const float* __restrict__ bias,
                                                    unsigned short* __restrict__ C, int ldc) {
    __shared__ unsigned short As[128 * LP];
    __shared__ unsigned short Bs[128 * LP];
    int tid = threadIdx.x;
    int m0 = blockIdx.x * 128;
    int n0 = blockIdx.y * 128;

    int lane = tid & 63;
    int wave = tid >> 6;
    int wm = (wave & 1) * 64;
    int wn = (wave >> 1) * 64;
    int lm = lane & 15;
    int lk = (lane >> 4) * 8;

    float4v acc[4][4];
    #pragma unroll
    for (int i = 0; i < 4; i++)
        #pragma unroll
        for (int j = 0; j < 4; j++) acc[i][j] = (float4v)0.f;

    int sr = tid >> 3;
    int sc = (tid & 7) * 8;

    for (int ks = 0; ks < lda; ks += 64) {
        if (ks) __syncthreads();
        int kk = ks + sc;
        #pragma unroll
        for (int rr = 0; rr < 128; rr += 32) {
            int r = sr + rr;
            int gm = m0 + r; if (gm > M - 1) gm = M - 1;
            *(ulonglong2*)&As[r * LP + sc] = *(const ulonglong2*)(A + (size_t)gm * lda + kk);
            *(ulonglong2*)&Bs[r * LP + sc] = *(const ulonglong2*)(Bt + (size_t)(n0 + r) * lda + kk);
        }
        __syncthreads();

        #pragma unroll
        for (int k0 = 0; k0 < 64; k0 += 32) {
            short8v af[4], bf[4];
            #pragma unroll
            for (int i = 0; i < 4; i++)
                af[i] = *(const short8v*)&As[(wm + i * 16 + lm) * LP + k0 + lk];
            #pragma unroll
            for (int j = 0; j < 4; j++)
                bf[j] = *(const short8v*)&Bs[(wn + j * 16 + lm) * LP + k0 + lk];
            #pragma unroll
            for (int i = 0; i < 4; i++)
                #pragma unroll
                for (int j = 0; j < 4; j++)
                    acc[i][j] = __builtin_amdgcn_mfma_f32_16x16x32_bf16(af[i], bf[j], acc[i][j], 0, 0, 0);
        }
    }

    int r0b = (lane >> 4) * 4;
    #pragma unroll
    for (int i = 0; i < 4; i++) {
        #pragma unroll
        for (int j = 0; j < 4; j++) {
            int cc = n0 + wn + j * 16 + lm;
            float bv = (bias != nullptr) ? bias[cc] : 0.f;
            #pragma unroll
            for (int r = 0; r < 4; r++) {
                int m = m0 + wm + i * 16 + r0b + r;
                if (m < M) {
                    float v = acc[i][j][r];
                    if (bias != nullptr) v = fmaxf(v + bv, 0.f);
                    C[(size_t)m * ldc + cc] = f2bf(v);
                }
            }
        }
    }
}

// ---------------- layer-3 fused GEMM+pq ----------------
__global__ __launch_bounds__(256) void mgemm_pq_kernel(const unsigned short* __restrict__ A, int lda,
                                                       const unsigned short* __restrict__ Bt, int M,
                                                       const float* __restrict__ bias,
                                                       const float* __restrict__ Wl4, const float* __restrict__ Wr4,
                                                       const float* __restrict__ b4,
                                                       float* __restrict__ p, float* __restrict__ q) {
    __shared__ unsigned short As[128 * LP];
    __shared__ unsigned short Bs[128 * LP];
    __shared__ float psA[2][128], qsA[2][128];
    int tid = threadIdx.x;
    int m0 = blockIdx.x * 128;

    int lane = tid & 63;
    int wave = tid >> 6;
    int wm = (wave & 1) * 64;
    int wn = (wave >> 1) * 64;
    int lm = lane & 15;
    int lk = (lane >> 4) * 8;

    float4v acc[4][4];
    #pragma unroll
    for (int i = 0; i < 4; i++)
        #pragma unroll
        for (int j = 0; j < 4; j++) acc[i][j] = (float4v)0.f;

    int sr = tid >> 3;
    int sc = (tid & 7) * 8;

    for (int ks = 0; ks < lda; ks += 64) {
        if (ks) __syncthreads();
        int kk = ks + sc;
        #pragma unroll
        for (int rr = 0; rr < 128; rr += 32) {
            int r = sr + rr;
            int gm = m0 + r; if (gm > M - 1) gm = M - 1;
            *(ulonglong2*)&As[r * LP + sc] = *(const ulonglong2*)(A + (size_t)gm * lda + kk);
            *(ulonglong2*)&Bs[r * LP + sc] = *(const ulonglong2*)(Bt + (size_t)r * lda + kk);
        }
        __syncthreads();

        #pragma unroll
        for (int k0 = 0; k0 < 64; k0 += 32) {
            short8v af[4], bf[4];
            #pragma unroll
            for (int i = 0; i < 4; i++)
                af[i] = *(const short8v*)&As[(wm + i * 16 + lm) * LP + k0 + lk];
            #pragma unroll
            for (int j = 0; j < 4; j++)
                bf[j] = *(const short8v*)&Bs[(wn + j * 16 + lm) * LP + k0 + lk];
            #pragma unroll
            for (int i = 0; i < 4; i++)
                #pragma unroll
                for (int j = 0; j < 4; j++)
                    acc[i][j] = __builtin_amdgcn_mfma_f32_16x16x32_bf16(af[i], bf[j], acc[i][j], 0, 0, 0);
        }
    }

    int qd = lane >> 4;
    int wnidx = wave >> 1;
    float b3v[4], wlv[4], wrv[4];
    #pragma unroll
    for (int j = 0; j < 4; j++) {
        int cc = wn + j * 16 + lm;
        b3v[j] = bias[cc]; wlv[j] = Wl4[cc]; wrv[j] = Wr4[cc];
    }
    #pragma unroll
    for (int i = 0; i < 4; i++) {
        #pragma unroll
        for (int r = 0; r < 4; r++) {
            float pp = 0.f, qq = 0.f;
            #pragma unroll
            for (int j = 0; j < 4; j++) {
                float hv = fmaxf(acc[i][j][r] + b3v[j], 0.f);
                pp += hv * wlv[j]; qq += hv * wrv[j];
            }
            #pragma unroll
            for (int off = 1; off < 16; off <<= 1) {
                pp += __shfl_xor(pp, off);
                qq += __shfl_xor(qq, off);
            }
            if (lm == 0) {
                int m = wm + i * 16 + qd * 4 + r;
                psA[wnidx][m] = pp;
                qsA[wnidx][m] = qq;
            }
        }
    }
    __syncthreads();
    if (wnidx == 0 && lm == 0) {
        float b4v = b4[0];
        #pragma unroll
        for (int i = 0; i < 4; i++) {
            #pragma unroll
            for (int r = 0; r < 4; r++) {
                int m = wm + i * 16 + qd * 4 + r;
                int gm = m0 + m;
                if (gm < M) {
                    p[gm] = psA[0][m] + psA[1][m];
                    q[gm] = qsA[0][m] + qsA[1][m] + b4v;
                }
            }
        }
    }
}

__global__ __launch_bounds__(256) void final_kernel(const float* __restrict__ p, const float* __restrict__ q,
                                                    const int* __restrict__ row_ptr, const int* __restrict__ col,
                                                    float* __restrict__ out) {
    int i = blockIdx.x * 256 + threadIdx.x;   // original node id
    if (i >= N_NODES) return;
    int s = row_ptr[i], e = row_ptr[i + 1];
    float acc = 0.f;
    int t = s;
    for (; t + 3 < e; t += 4)
        acc += p[col[t]] + p[col[t + 1]] + p[col[t + 2]] + p[col[t + 3]];
    for (; t < e; t++) acc += p[col[t]];
    float di = 1.0f / fmaxf((float)(e - s), 1.0f);
    out[i] = acc * di + q[i];
}

// ---------------- launch ----------------

extern "C" void kernel_launch(void* const* d_in, const int* in_sizes, int n_in,
                              void* d_out, int out_size, void* d_ws, size_t ws_size,
                              hipStream_t stream) {
    const float* x    = (const float*)d_in[0];
    const int*   ei   = (const int*)d_in[1];
    const float* Wl1  = (const float*)d_in[2];
    const float* Wr1  = (const float*)d_in[3];
    const float* b1   = (const float*)d_in[4];
    const float* ln_g = (const float*)d_in[5];
    const float* ln_b = (const float*)d_in[6];
    const float* Wres = (const float*)d_in[7];
    const float* bres = (const float*)d_in[8];
    const float* Wl2  = (const float*)d_in[9];
    const float* Wr2  = (const float*)d_in[10];
    const float* b2   = (const float*)d_in[11];
    const float* Wl3  = (const float*)d_in[12];
    const float* Wr3  = (const float*)d_in[13];
    const float* b3   = (const float*)d_in[14];
    const float* Wl4  = (const float*)d_in[15];
    const float* Wr4  = (const float*)d_in[16];
    const float* b4   = (const float*)d_in[17];
    float* out = (float*)d_out;

    char* w = (char*)d_ws;
    size_t off = 0;
    auto alloc = [&](size_t bytes) -> void* {
        off = (off + 255) & ~(size_t)255;
        void* pp = w + off;
        off += bytes;
        return pp;
    };

    int*   deg        = (int*)alloc(N_NODES * 4);
    int*   row_ptr    = (int*)alloc((N_NODES + 1) * 4);
    int*   bsum       = (int*)alloc(512);
    int*   col        = (int*)alloc(N_EDGES * 4);
    int*   bucket_off = (int*)alloc((NBKT + 1) * 4);
    int*   bh2        = (int*)alloc(BH2_N * 4);
    int*   bh         = (int*)alloc(64 * SORT_BLOCKS * 4);
    int*   ord        = (int*)alloc(N_NODES * 4);       // sorted slot -> original node
    unsigned short* Btw  = (unsigned short*)alloc(128 * 256 * 2);
    unsigned short* xcat = (unsigned short*)alloc((size_t)N_NODES * 128 * 2);  // [x | aggx] bf16
    unsigned short* hcat = (unsigned short*)alloc((size_t)N_NODES * 256 * 2);  // [h | aggh] bf16
    int*   packed  = (int*)alloc((size_t)N_EDGES * 4);   // CSR build scratch
    float* p       = (float*)alloc(N_NODES * 4);
    float* q       = (float*)alloc(N_NODES * 4);
    (void)ws_size; (void)n_in; (void)in_sizes; (void)out_size;

    const int NB = (N_NODES + 255) / 256;
    const int BHB = (BH2_N + 1023) / 1024;              // 92
    const int MB = (N_NODES + 127) / 128;               // 782

    // --- CSR build (original space): hist -> scan -> scatter -> deg+row_ptr; degree sort -> ord; fill ---
    bkt_hist_kernel<<<SCAT_BLOCKS, 256, 0, stream>>>(ei, bh2);
    gscan_a_kernel<<<BHB, 256, 0, stream>>>(bh2, bsum, BH2_N);
    scan_b_kernel<<<1, 128, 0, stream>>>(bsum, BHB);
    gscan_c_kernel<<<BHB, 256, 0, stream>>>(bh2, bsum, BH2_N);
    extract_off_kernel<<<(NBKT + 256) / 256, 256, 0, stream>>>(bh2, bucket_off);
    bkt_scatter2_kernel<<<SCAT_BLOCKS, 256, 0, stream>>>(ei, bh2, packed);
    bkt_degrow_kernel<<<NBKT, 256, 0, stream>>>(packed, bucket_off, deg, row_ptr);
    dsort_hist_kernel<<<SORT_BLOCKS, 256, 0, stream>>>(deg, bh);
    dsort_scan_kernel<<<1, 256, 0, stream>>>(bh);
    dsort_scat_kernel<<<SORT_BLOCKS, 256, 0, stream>>>(deg, bh, ord);
    bkt_fill3_kernel<<<NBKT, 256, 0, stream>>>(packed, bucket_off, row_ptr, col);

    // --- layer 1: xcat = [x | mean-agg(x)]; fused GEMM+LN -> hcat[:,0:128] ---
    xbf_kernel<<<(N_NODES * 16 + 255) / 256, 256, 0, stream>>>(x, xcat);
    agg64_kernel<<<(N_NODES + 15) / 16, 256, 0, stream>>>(xcat, row_ptr, col, ord);
    wprep1_kernel<<<128, 256, 0, stream>>>(Wr1, Wl1, Wres, Btw);
    mgemm1_ln_kernel<<<MB, 256, 0, stream>>>(xcat, Btw, N_NODES, b1, ln_g, ln_b, bres, hcat);

    // --- layer 2: agg(h) -> hcat[:,128:256]; GEMM [h|aggh] -> hcat[:,0:128] (bias+relu) ---
    agg128_kernel<<<(N_NODES + 7) / 8, 256, 0, stream>>>(hcat, row_ptr, col, ord);
    wprep23_kernel<<<128, 256, 0, stream>>>(Wl2, Wr2, Btw);
    mgemm_kernel<<<dim3(MB, 1), 256, 0, stream>>>(hcat, 256, Btw, N_NODES, b2, hcat, 256);

    // --- layer 3: agg(h) -> hcat[:,128:256]; fused GEMM+pq -> p, q (h3 never stored) ---
    agg128_kernel<<<(N_NODES + 7) / 8, 256, 0, stream>>>(hcat, row_ptr, col, ord);
    wprep23_kernel<<<128, 256, 0, stream>>>(Wl3, Wr3, Btw);
    mgemm_pq_kernel<<<MB, 256, 0, stream>>>(hcat, 256, Btw, N_NODES, b3, Wl4, Wr4, b4, p, q);

    // --- final ---
    final_kernel<<<NB, 256, 0, stream>>>(p, q, row_ptr, col, out);
}

// Round 14
// 438.320 us; speedup vs baseline: 1.1198x; 1.0244x over previous
//
#include <hip/hip_runtime.h>
#include <hip/hip_bf16.h>

#define N_NODES 100000
#define N_EDGES 1600000

#define NBKT 782                 // ceil(N_NODES / 128)
#define SCAT_BLOCKS 240
#define BKT_CHUNK 6667           // ceil(N_EDGES / 240)
#define LP 72                    // padded LDS row length in shorts (64 + 8)

#define SORT_BLOCKS 40
#define SORT_CHUNK 2500          // 40 * 2500 = 100000
#define BH2_N (NBKT * SCAT_BLOCKS)   // 187680

typedef __attribute__((ext_vector_type(8))) short short8v;
typedef __attribute__((ext_vector_type(4))) float float4v;

__device__ __forceinline__ unsigned short f2bf(float f) {
    unsigned int u = __float_as_uint(f);
    u = (u + 0x7FFFu + ((u >> 16) & 1u)) >> 16;   // RTNE
    return (unsigned short)u;
}
__device__ __forceinline__ float bf2f(unsigned short b) {
    return __uint_as_float((unsigned int)b << 16);
}

// ---------------- CSR build (ORIGINAL node space; bucket = dst>>7) ----------------

__global__ __launch_bounds__(256) void bkt_hist_kernel(const int* __restrict__ ei, int* __restrict__ bh2) {
    __shared__ int h[NBKT];
    int tid = threadIdx.x;
    for (int i = tid; i < NBKT; i += 256) h[i] = 0;
    __syncthreads();
    int start = blockIdx.x * BKT_CHUNK;
    int end = start + BKT_CHUNK; if (end > N_EDGES) end = N_EDGES;
    for (int i = start + tid; i < end; i += 256) {
        int d = ei[N_EDGES + i];
        atomicAdd(&h[d >> 7], 1);
    }
    __syncthreads();
    for (int i = tid; i < NBKT; i += 256) bh2[i * SCAT_BLOCKS + blockIdx.x] = h[i];
}

__global__ __launch_bounds__(256) void gscan_a_kernel(const int* __restrict__ in, int* __restrict__ bsum, int n) {
    __shared__ int lds[256];
    int tid = threadIdx.x;
    int base = blockIdx.x * 1024 + tid * 4;
    int s = 0;
    #pragma unroll
    for (int i = 0; i < 4; i++) s += (base + i < n) ? in[base + i] : 0;
    lds[tid] = s;
    __syncthreads();
    for (int off = 128; off; off >>= 1) {
        if (tid < off) lds[tid] += lds[tid + off];
        __syncthreads();
    }
    if (tid == 0) bsum[blockIdx.x] = lds[0];
}

// parallel exclusive scan of up to 256 block sums
__global__ __launch_bounds__(256) void scan_b_kernel(int* __restrict__ bsum, int nb) {
    __shared__ int lds[256];
    int tid = threadIdx.x;
    int v = (tid < nb) ? bsum[tid] : 0;
    lds[tid] = v;
    __syncthreads();
    for (int off = 1; off < 256; off <<= 1) {
        int y = 0;
        if (tid >= off) y = lds[tid - off];
        __syncthreads();
        if (tid >= off) lds[tid] += y;
        __syncthreads();
    }
    if (tid < nb) bsum[tid] = lds[tid] - v;   // exclusive
}

__global__ __launch_bounds__(256) void gscan_c_kernel(int* __restrict__ data, const int* __restrict__ bsum, int n) {
    __shared__ int lds[256];
    int tid = threadIdx.x;
    int base = blockIdx.x * 1024 + tid * 4;
    int v[4];
    int s = 0;
    #pragma unroll
    for (int i = 0; i < 4; i++) {
        v[i] = (base + i < n) ? data[base + i] : 0;
        s += v[i];
    }
    lds[tid] = s;
    __syncthreads();
    for (int off = 1; off < 256; off <<= 1) {
        int y = 0;
        if (tid >= off) y = lds[tid - off];
        __syncthreads();
        if (tid >= off) lds[tid] += y;
        __syncthreads();
    }
    int run = bsum[blockIdx.x] + lds[tid] - s;
    #pragma unroll
    for (int i = 0; i < 4; i++) {
        if (base + i < n) data[base + i] = run;
        run += v[i];
    }
}

__global__ __launch_bounds__(256) void bkt_scatter2_kernel(const int* __restrict__ ei, const int* __restrict__ bh2,
                                                           int* __restrict__ packed) {
    __shared__ int h[NBKT];
    __shared__ int base[NBKT];
    int tid = threadIdx.x;
    for (int i = tid; i < NBKT; i += 256) { h[i] = 0; base[i] = bh2[i * SCAT_BLOCKS + blockIdx.x]; }
    __syncthreads();
    int start = blockIdx.x * BKT_CHUNK;
    int end = start + BKT_CHUNK; if (end > N_EDGES) end = N_EDGES;
    for (int i = start + tid; i < end; i += 256) {
        int s = ei[i];
        int d = ei[N_EDGES + i];
        int b = d >> 7;
        int pos = base[b] + atomicAdd(&h[b], 1);
        packed[pos] = (s << 7) | (d & 127);
    }
}

// merged: per-bucket degree count + LDS scan -> deg[], row_ptr[]; then fill col from the
// (L2-hot) packed segment. Bucket bounds read directly from scanned bh2.
__global__ __launch_bounds__(256) void bkt_build_kernel(const int* __restrict__ packed, const int* __restrict__ bh2,
                                                        int* __restrict__ deg, int* __restrict__ row_ptr,
                                                        int* __restrict__ col) {
    __shared__ int c[128];
    __shared__ int rp[128];
    int tid = threadIdx.x;
    int s0 = bh2[blockIdx.x * SCAT_BLOCKS];
    int s1 = (blockIdx.x + 1 < NBKT) ? bh2[(blockIdx.x + 1) * SCAT_BLOCKS] : N_EDGES;
    if (tid < 128) c[tid] = 0;
    __syncthreads();
    for (int i = s0 + tid; i < s1; i += 256) atomicAdd(&c[packed[i] & 127], 1);
    __syncthreads();
    if (tid < 128) rp[tid] = c[tid];
    __syncthreads();
    for (int off = 1; off < 128; off <<= 1) {
        int y = 0;
        if (tid >= off && tid < 128) y = rp[tid - off];
        __syncthreads();
        if (tid >= off && tid < 128) rp[tid] += y;
        __syncthreads();
    }
    int node = blockIdx.x * 128 + tid;
    if (tid < 128) {
        rp[tid] = s0 + rp[tid] - c[tid];   // exclusive in-bucket prefix + bucket base
        if (node < N_NODES) {
            deg[node] = c[tid];
            row_ptr[node] = rp[tid];
        }
        c[tid] = 0;
    }
    if (blockIdx.x == 0 && tid == 0) row_ptr[N_NODES] = N_EDGES;
    __syncthreads();
    for (int i = s0 + tid; i < s1; i += 256) {
        int p = packed[i];
        int dl = p & 127;
        int pos = rp[dl] + atomicAdd(&c[dl], 1);
        col[pos] = p >> 7;
    }
}

// ---------------- degree counting sort -> ord[] only (slot -> original node) ----------------
__global__ __launch_bounds__(256) void dsort_hist_kernel(const int* __restrict__ deg, int* __restrict__ bh) {
    __shared__ int h[64];
    int tid = threadIdx.x;
    if (tid < 64) h[tid] = 0;
    __syncthreads();
    int start = blockIdx.x * SORT_CHUNK;
    int end = start + SORT_CHUNK; if (end > N_NODES) end = N_NODES;
    for (int i = start + tid; i < end; i += 256) atomicAdd(&h[min(deg[i], 63)], 1);
    __syncthreads();
    if (tid < 64) bh[tid * SORT_BLOCKS + blockIdx.x] = h[tid];
}

__global__ __launch_bounds__(256) void dsort_scan_kernel(int* __restrict__ bh) {
    __shared__ int ps[256];
    int tid = threadIdx.x;
    int v[10];
    int s = 0;
    #pragma unroll
    for (int k = 0; k < 10; k++) { v[k] = bh[tid * 10 + k]; s += v[k]; }
    ps[tid] = s;
    __syncthreads();
    for (int off = 1; off < 256; off <<= 1) {
        int y = 0;
        if (tid >= off) y = ps[tid - off];
        __syncthreads();
        if (tid >= off) ps[tid] += y;
        __syncthreads();
    }
    int run = ps[tid] - s;
    #pragma unroll
    for (int k = 0; k < 10; k++) { int t = v[k]; bh[tid * 10 + k] = run; run += t; }
}

__global__ __launch_bounds__(256) void dsort_scat_kernel(const int* __restrict__ deg, const int* __restrict__ bh,
                                                         int* __restrict__ ord) {
    __shared__ int h[64];
    __shared__ int base[64];
    int tid = threadIdx.x;
    if (tid < 64) { h[tid] = 0; base[tid] = bh[tid * SORT_BLOCKS + blockIdx.x]; }
    __syncthreads();
    int start = blockIdx.x * SORT_CHUNK;
    int end = start + SORT_CHUNK; if (end > N_NODES) end = N_NODES;
    for (int i = start + tid; i < end; i += 256) {
        int b = min(deg[i], 63);
        int pos = base[b] + atomicAdd(&h[b], 1);
        ord[pos] = i;
    }
}

// ---------------- x (fp32) -> xcat[:,0:64] bf16, pure streaming ----------------
__global__ __launch_bounds__(256) void xbf_kernel(const float* __restrict__ x, unsigned short* __restrict__ xcat) {
    int idx = blockIdx.x * 256 + threadIdx.x;   // one float4 per thread
    if (idx < N_NODES * 16) {
        int node = idx >> 4;
        int f0 = (idx & 15) * 4;
        float4 v = *(const float4*)(x + (size_t)idx * 4);
        ushort4 o;
        o.x = f2bf(v.x); o.y = f2bf(v.y); o.z = f2bf(v.z); o.w = f2bf(v.w);
        *(ushort4*)(xcat + (size_t)node * 128 + f0) = o;
    }
}

#define ACC4(u) { a0 += bf2f(u.x); a1 += bf2f(u.y); a2 += bf2f(u.z); a3 += bf2f(u.w); }

// ---------------- layer-1 agg: mean of xcat[j,0:64] -> xcat[i,64:128]; 16 lanes/node ----------------
__global__ __launch_bounds__(256) void agg64_kernel(unsigned short* __restrict__ xcat,
                                                    const int* __restrict__ row_ptr, const int* __restrict__ col,
                                                    const int* __restrict__ ord) {
    int tid = threadIdx.x;
    int slot = blockIdx.x * 16 + (tid >> 4);
    if (slot >= N_NODES) return;
    int i = ord[slot];
    int f0 = (tid & 15) * 4;
    int s = row_ptr[i], e = row_ptr[i + 1];
    float a0 = 0.f, a1 = 0.f, a2 = 0.f, a3 = 0.f;
    int t = s;
    while (t + 7 < e) {
        int j0 = col[t], j1 = col[t + 1], j2 = col[t + 2], j3 = col[t + 3];
        int j4 = col[t + 4], j5 = col[t + 5], j6 = col[t + 6], j7 = col[t + 7];
        ushort4 u0 = *(const ushort4*)(xcat + (size_t)j0 * 128 + f0);
        ushort4 u1 = *(const ushort4*)(xcat + (size_t)j1 * 128 + f0);
        ushort4 u2 = *(const ushort4*)(xcat + (size_t)j2 * 128 + f0);
        ushort4 u3 = *(const ushort4*)(xcat + (size_t)j3 * 128 + f0);
        ushort4 u4 = *(const ushort4*)(xcat + (size_t)j4 * 128 + f0);
        ushort4 u5 = *(const ushort4*)(xcat + (size_t)j5 * 128 + f0);
        ushort4 u6 = *(const ushort4*)(xcat + (size_t)j6 * 128 + f0);
        ushort4 u7 = *(const ushort4*)(xcat + (size_t)j7 * 128 + f0);
        ACC4(u0) ACC4(u1) ACC4(u2) ACC4(u3) ACC4(u4) ACC4(u5) ACC4(u6) ACC4(u7)
        t += 8;
    }
    if (t + 3 < e) {
        int j0 = col[t], j1 = col[t + 1], j2 = col[t + 2], j3 = col[t + 3];
        ushort4 u0 = *(const ushort4*)(xcat + (size_t)j0 * 128 + f0);
        ushort4 u1 = *(const ushort4*)(xcat + (size_t)j1 * 128 + f0);
        ushort4 u2 = *(const ushort4*)(xcat + (size_t)j2 * 128 + f0);
        ushort4 u3 = *(const ushort4*)(xcat + (size_t)j3 * 128 + f0);
        ACC4(u0) ACC4(u1) ACC4(u2) ACC4(u3)
        t += 4;
    }
    if (t + 1 < e) {
        int j0 = col[t], j1 = col[t + 1];
        ushort4 u0 = *(const ushort4*)(xcat + (size_t)j0 * 128 + f0);
        ushort4 u1 = *(const ushort4*)(xcat + (size_t)j1 * 128 + f0);
        ACC4(u0) ACC4(u1)
        t += 2;
    }
    if (t < e) {
        ushort4 u0 = *(const ushort4*)(xcat + (size_t)col[t] * 128 + f0);
        ACC4(u0)
    }
    float di = 1.0f / fmaxf((float)(e - s), 1.0f);
    ushort4 o;
    o.x = f2bf(a0 * di); o.y = f2bf(a1 * di); o.z = f2bf(a2 * di); o.w = f2bf(a3 * di);
    *(ushort4*)(xcat + (size_t)i * 128 + 64 + f0) = o;
}

// ---------------- layers 2/3 agg: mean of hcat[j,0:128] -> hcat[i,128:256]; 32 lanes/node ----------------
__global__ __launch_bounds__(256) void agg128_kernel(unsigned short* __restrict__ hcat,
                                                     const int* __restrict__ row_ptr, const int* __restrict__ col,
                                                     const int* __restrict__ ord) {
    int tid = threadIdx.x;
    int slot = blockIdx.x * 8 + (tid >> 5);
    if (slot >= N_NODES) return;
    int i = ord[slot];
    int f0 = (tid & 31) * 4;
    int s = row_ptr[i], e = row_ptr[i + 1];
    float a0 = 0.f, a1 = 0.f, a2 = 0.f, a3 = 0.f;
    int t = s;
    while (t + 7 < e) {
        int j0 = col[t], j1 = col[t + 1], j2 = col[t + 2], j3 = col[t + 3];
        int j4 = col[t + 4], j5 = col[t + 5], j6 = col[t + 6], j7 = col[t + 7];
        ushort4 u0 = *(const ushort4*)(hcat + (size_t)j0 * 256 + f0);
        ushort4 u1 = *(const ushort4*)(hcat + (size_t)j1 * 256 + f0);
        ushort4 u2 = *(const ushort4*)(hcat + (size_t)j2 * 256 + f0);
        ushort4 u3 = *(const ushort4*)(hcat + (size_t)j3 * 256 + f0);
        ushort4 u4 = *(const ushort4*)(hcat + (size_t)j4 * 256 + f0);
        ushort4 u5 = *(const ushort4*)(hcat + (size_t)j5 * 256 + f0);
        ushort4 u6 = *(const ushort4*)(hcat + (size_t)j6 * 256 + f0);
        ushort4 u7 = *(const ushort4*)(hcat + (size_t)j7 * 256 + f0);
        ACC4(u0) ACC4(u1) ACC4(u2) ACC4(u3) ACC4(u4) ACC4(u5) ACC4(u6) ACC4(u7)
        t += 8;
    }
    if (t + 3 < e) {
        int j0 = col[t], j1 = col[t + 1], j2 = col[t + 2], j3 = col[t + 3];
        ushort4 u0 = *(const ushort4*)(hcat + (size_t)j0 * 256 + f0);
        ushort4 u1 = *(const ushort4*)(hcat + (size_t)j1 * 256 + f0);
        ushort4 u2 = *(const ushort4*)(hcat + (size_t)j2 * 256 + f0);
        ushort4 u3 = *(const ushort4*)(hcat + (size_t)j3 * 256 + f0);
        ACC4(u0) ACC4(u1) ACC4(u2) ACC4(u3)
        t += 4;
    }
    if (t + 1 < e) {
        int j0 = col[t], j1 = col[t + 1];
        ushort4 u0 = *(const ushort4*)(hcat + (size_t)j0 * 256 + f0);
        ushort4 u1 = *(const ushort4*)(hcat + (size_t)j1 * 256 + f0);
        ACC4(u0) ACC4(u1)
        t += 2;
    }
    if (t < e) {
        ushort4 u0 = *(const ushort4*)(hcat + (size_t)col[t] * 256 + f0);
        ACC4(u0)
    }
    float di = 1.0f / fmaxf((float)(e - s), 1.0f);
    ushort4 o;
    o.x = f2bf(a0 * di); o.y = f2bf(a1 * di); o.z = f2bf(a2 * di); o.w = f2bf(a3 * di);
    *(ushort4*)(hcat + (size_t)i * 256 + 128 + f0) = o;
}

// ---------------- weight prep (transposed bf16) ----------------
__global__ __launch_bounds__(256) void wprep1_kernel(const float* __restrict__ Wr1, const float* __restrict__ Wl1,
                                                     const float* __restrict__ Wres, unsigned short* __restrict__ Bt) {
    int idx = blockIdx.x * 256 + threadIdx.x;   // n*128 + k
    if (idx >= 256 * 128) return;
    int n = idx >> 7;
    int k = idx & 127;
    float v;
    if (n < 128) v = (k < 64) ? Wr1[k * 128 + n] : Wl1[(k - 64) * 128 + n];
    else         v = (k < 64) ? Wres[k * 128 + (n - 128)] : 0.f;
    Bt[idx] = f2bf(v);
}

__global__ __launch_bounds__(256) void wprep23_kernel(const float* __restrict__ Wl, const float* __restrict__ Wr,
                                                      unsigned short* __restrict__ Bt) {
    int idx = blockIdx.x * 256 + threadIdx.x;   // n*256 + k
    if (idx >= 128 * 256) return;
    int n = idx >> 8;
    int k = idx & 255;
    float v = (k < 128) ? Wr[k * 128 + n] : Wl[(k - 128) * 128 + n];
    Bt[idx] = f2bf(v);
}

// ---------------- layer-1 fused GEMM+LN ----------------
__global__ __launch_bounds__(256) void mgemm1_ln_kernel(const unsigned short* __restrict__ A,
                                                        const unsigned short* __restrict__ Bt, int M,
                                                        const float* __restrict__ b1, const float* __restrict__ ln_g,
                                                        const float* __restrict__ ln_b, const float* __restrict__ bres,
                                                        unsigned short* __restrict__ hcat) {
    __shared__ unsigned short As[128 * LP];
    __shared__ unsigned short Bs[256 * LP];
    __shared__ float lsum[2][128], lsq[2][128];
    int tid = threadIdx.x;
    int m0 = blockIdx.x * 128;

    int lane = tid & 63;
    int wave = tid >> 6;
    int wm = (wave & 1) * 64;
    int wn = (wave >> 1) * 64;
    int lm = lane & 15;
    int lk = (lane >> 4) * 8;

    float4v accT[4][4], accR[4][4];
    #pragma unroll
    for (int i = 0; i < 4; i++)
        #pragma unroll
        for (int j = 0; j < 4; j++) { accT[i][j] = (float4v)0.f; accR[i][j] = (float4v)0.f; }

    int sr = tid >> 3;
    int sc = (tid & 7) * 8;

    for (int ks = 0; ks < 128; ks += 64) {
        if (ks) __syncthreads();
        int kk = ks + sc;
        #pragma unroll
        for (int rr = 0; rr < 384; rr += 32) {
            int r = sr + rr;
            if (r < 128) {
                int gm = m0 + r; if (gm > M - 1) gm = M - 1;
                *(ulonglong2*)&As[r * LP + sc] = *(const ulonglong2*)(A + (size_t)gm * 128 + kk);
            } else {
                int br = r - 128;
                *(ulonglong2*)&Bs[br * LP + sc] = *(const ulonglong2*)(Bt + (size_t)br * 128 + kk);
            }
        }
        __syncthreads();

        #pragma unroll
        for (int k0 = 0; k0 < 64; k0 += 32) {
            short8v af[4], bfT[4], bfR[4];
            #pragma unroll
            for (int i = 0; i < 4; i++)
                af[i] = *(const short8v*)&As[(wm + i * 16 + lm) * LP + k0 + lk];
            #pragma unroll
            for (int j = 0; j < 4; j++) {
                bfT[j] = *(const short8v*)&Bs[(wn + j * 16 + lm) * LP + k0 + lk];
                bfR[j] = *(const short8v*)&Bs[(128 + wn + j * 16 + lm) * LP + k0 + lk];
            }
            #pragma unroll
            for (int i = 0; i < 4; i++)
                #pragma unroll
                for (int j = 0; j < 4; j++) {
                    accT[i][j] = __builtin_amdgcn_mfma_f32_16x16x32_bf16(af[i], bfT[j], accT[i][j], 0, 0, 0);
                    accR[i][j] = __builtin_amdgcn_mfma_f32_16x16x32_bf16(af[i], bfR[j], accR[i][j], 0, 0, 0);
                }
        }
    }

    int q = lane >> 4;
    int wnidx = wave >> 1;
    float b1v[4], gv[4], bbv[4], brv[4];
    #pragma unroll
    for (int j = 0; j < 4; j++) {
        int cc = wn + j * 16 + lm;
        b1v[j] = b1[cc]; gv[j] = ln_g[cc]; bbv[j] = ln_b[cc]; brv[j] = bres[cc];
    }
    #pragma unroll
    for (int i = 0; i < 4; i++) {
        #pragma unroll
        for (int r = 0; r < 4; r++) {
            float sp = 0.f, sq = 0.f;
            #pragma unroll
            for (int j = 0; j < 4; j++) {
                float tv = accT[i][j][r] + b1v[j];
                sp += tv; sq += tv * tv;
            }
            #pragma unroll
            for (int off = 1; off < 16; off <<= 1) {
                sp += __shfl_xor(sp, off);
                sq += __shfl_xor(sq, off);
            }
            if (lm == 0) {
                int m = wm + i * 16 + q * 4 + r;
                lsum[wnidx][m] = sp;
                lsq[wnidx][m] = sq;
            }
        }
    }
    __syncthreads();
    #pragma unroll
    for (int i = 0; i < 4; i++) {
        #pragma unroll
        for (int r = 0; r < 4; r++) {
            int m = wm + i * 16 + q * 4 + r;
            float sum = lsum[0][m] + lsum[1][m];
            float s2 = lsq[0][m] + lsq[1][m];
            float mu = sum * (1.f / 128.f);
            float var = s2 * (1.f / 128.f) - mu * mu;
            float rstd = rsqrtf(var + 1e-5f);
            int gm = m0 + m;
            if (gm < M) {
                #pragma unroll
                for (int j = 0; j < 4; j++) {
                    float tv = accT[i][j][r] + b1v[j];
                    float y = fmaxf((tv - mu) * rstd * gv[j] + bbv[j], 0.f) + accR[i][j][r] + brv[j];
                    hcat[(size_t)gm * 256 + wn + j * 16 + lm] = f2bf(y);
                }
            }
        }
    }
}

// ---------------- MFMA bf16 GEMM (layer 2): hcat[:,0:128] = relu(hcat@Bt^T + bias) ----------------
__global__ __launch_bounds__(256) void mgemm_kernel(const unsigned short* __restrict__ A, int lda,
                                                    const unsigned short* __restrict__ Bt, int M,
                                                    const float* __restrict__ bias,
                                                    unsigned short* __restrict__ C, int ldc) {
    __shared__ unsigned short As[128 * LP];
    __shared__ unsigned short Bs[128 * LP];
    int tid = threadIdx.x;
    int m0 = blockIdx.x * 128;
    int n0 = blockIdx.y * 128;

    int lane = tid & 63;
    int wave = tid >> 6;
    int wm = (wave & 1) * 64;
    int wn = (wave >> 1) * 64;
    int lm = lane & 15;
    int lk = (lane >> 4) * 8;

    float4v acc[4][4];
    #pragma unroll
    for (int i = 0; i < 4; i++)
        #pragma unroll
        for (int j = 0; j < 4; j++) acc[i][j] = (float4v)0.f;

    int sr = tid >> 3;
    int sc = (tid & 7) * 8;

    for (int ks = 0; ks < lda; ks += 64) {
        if (ks) __syncthreads();
        int kk = ks + sc;
        #pragma unroll
        for (int rr = 0; rr < 128; rr += 32) {
            int r = sr + rr;
            int gm = m0 + r; if (gm > M - 1) gm = M - 1;
            *(ulonglong2*)&As[r * LP + sc] = *(const ulonglong2*)(A + (size_t)gm * lda + kk);
            *(ulonglong2*)&Bs[r * LP + sc] = *(const ulonglong2*)(Bt + (size_t)(n0 + r) * lda + kk);
        }
        __syncthreads();

        #pragma unroll
        for (int k0 = 0; k0 < 64; k0 += 32) {
            short8v af[4], bf[4];
            #pragma unroll
            for (int i = 0; i < 4; i++)
                af[i] = *(const short8v*)&As[(wm + i * 16 + lm) * LP + k0 + lk];
            #pragma unroll
            for (int j = 0; j < 4; j++)
                bf[j] = *(const short8v*)&Bs[(wn + j * 16 + lm) * LP + k0 + lk];
            #pragma unroll
            for (int i = 0; i < 4; i++)
                #pragma unroll
                for (int j = 0; j < 4; j++)
                    acc[i][j] = __builtin_amdgcn_mfma_f32_16x16x32_bf16(af[i], bf[j], acc[i][j], 0, 0, 0);
        }
    }

    int r0b = (lane >> 4) * 4;
    #pragma unroll
    for (int i = 0; i < 4; i++) {
        #pragma unroll
        for (int j = 0; j < 4; j++) {
            int cc = n0 + wn + j * 16 + lm;
            float bv = (bias != nullptr) ? bias[cc] : 0.f;
            #pragma unroll
            for (int r = 0; r < 4; r++) {
                int m = m0 + wm + i * 16 + r0b + r;
                if (m < M) {
                    float v = acc[i][j][r];
                    if (bias != nullptr) v = fmaxf(v + bv, 0.f);
                    C[(size_t)m * ldc + cc] = f2bf(v);
                }
            }
        }
    }
}

// ---------------- layer-3 fused GEMM+pq ----------------
__global__ __launch_bounds__(256) void mgemm_pq_kernel(const unsigned short* __restrict__ A, int lda,
                                                       const unsigned short* __restrict__ Bt, int M,
                                                       const float* __restrict__ bias,
                                                       const float* __restrict__ Wl4, const float* __restrict__ Wr4,
                                                       const float* __restrict__ b4,
                                                       float* __restrict__ p, float* __restrict__ q) {
    __shared__ unsigned short As[128 * LP];
    __shared__ unsigned short Bs[128 * LP];
    __shared__ float psA[2][128], qsA[2][128];
    int tid = threadIdx.x;
    int m0 = blockIdx.x * 128;

    int lane = tid & 63;
    int wave = tid >> 6;
    int wm = (wave & 1) * 64;
    int wn = (wave >> 1) * 64;
    int lm = lane & 15;
    int lk = (lane >> 4) * 8;

    float4v acc[4][4];
    #pragma unroll
    for (int i = 0; i < 4; i++)
        #pragma unroll
        for (int j = 0; j < 4; j++) acc[i][j] = (float4v)0.f;

    int sr = tid >> 3;
    int sc = (tid & 7) * 8;

    for (int ks = 0; ks < lda; ks += 64) {
        if (ks) __syncthreads();
        int kk = ks + sc;
        #pragma unroll
        for (int rr = 0; rr < 128; rr += 32) {
            int r = sr + rr;
            int gm = m0 + r; if (gm > M - 1) gm = M - 1;
            *(ulonglong2*)&As[r * LP + sc] = *(const ulonglong2*)(A + (size_t)gm * lda + kk);
            *(ulonglong2*)&Bs[r * LP + sc] = *(const ulonglong2*)(Bt + (size_t)r * lda + kk);
        }
        __syncthreads();

        #pragma unroll
        for (int k0 = 0; k0 < 64; k0 += 32) {
            short8v af[4], bf[4];
            #pragma unroll
            for (int i = 0; i < 4; i++)
                af[i] = *(const short8v*)&As[(wm + i * 16 + lm) * LP + k0 + lk];
            #pragma unroll
            for (int j = 0; j < 4; j++)
                bf[j] = *(const short8v*)&Bs[(wn + j * 16 + lm) * LP + k0 + lk];
            #pragma unroll
            for (int i = 0; i < 4; i++)
                #pragma unroll
                for (int j = 0; j < 4; j++)
                    acc[i][j] = __builtin_amdgcn_mfma_f32_16x16x32_bf16(af[i], bf[j], acc[i][j], 0, 0, 0);
        }
    }

    int qd = lane >> 4;
    int wnidx = wave >> 1;
    float b3v[4], wlv[4], wrv[4];
    #pragma unroll
    for (int j = 0; j < 4; j++) {
        int cc = wn + j * 16 + lm;
        b3v[j] = bias[cc]; wlv[j] = Wl4[cc]; wrv[j] = Wr4[cc];
    }
    #pragma unroll
    for (int i = 0; i < 4; i++) {
        #pragma unroll
        for (int r = 0; r < 4; r++) {
            float pp = 0.f, qq = 0.f;
            #pragma unroll
            for (int j = 0; j < 4; j++) {
                float hv = fmaxf(acc[i][j][r] + b3v[j], 0.f);
                pp += hv * wlv[j]; qq += hv * wrv[j];
            }
            #pragma unroll
            for (int off = 1; off < 16; off <<= 1) {
                pp += __shfl_xor(pp, off);
                qq += __shfl_xor(qq, off);
            }
            if (lm == 0) {
                int m = wm + i * 16 + qd * 4 + r;
                psA[wnidx][m] = pp;
                qsA[wnidx][m] = qq;
            }
        }
    }
    __syncthreads();
    if (wnidx == 0 && lm == 0) {
        float b4v = b4[0];
        #pragma unroll
        for (int i = 0; i < 4; i++) {
            #pragma unroll
            for (int r = 0; r < 4; r++) {
                int m = wm + i * 16 + qd * 4 + r;
                int gm = m0 + m;
                if (gm < M) {
                    p[gm] = psA[0][m] + psA[1][m];
                    q[gm] = qsA[0][m] + qsA[1][m] + b4v;
                }
            }
        }
    }
}

__global__ __launch_bounds__(256) void final_kernel(const float* __restrict__ p, const float* __restrict__ q,
                                                    const int* __restrict__ row_ptr, const int* __restrict__ col,
                                                    float* __restrict__ out) {
    int i = blockIdx.x * 256 + threadIdx.x;   // original node id
    if (i >= N_NODES) return;
    int s = row_ptr[i], e = row_ptr[i + 1];
    float acc = 0.f;
    int t = s;
    for (; t + 3 < e; t += 4)
        acc += p[col[t]] + p[col[t + 1]] + p[col[t + 2]] + p[col[t + 3]];
    for (; t < e; t++) acc += p[col[t]];
    float di = 1.0f / fmaxf((float)(e - s), 1.0f);
    out[i] = acc * di + q[i];
}

// ---------------- launch ----------------

extern "C" void kernel_launch(void* const* d_in, const int* in_sizes, int n_in,
                              void* d_out, int out_size, void* d_ws, size_t ws_size,
                              hipStream_t stream) {
    const float* x    = (const float*)d_in[0];
    const int*   ei   = (const int*)d_in[1];
    const float* Wl1  = (const float*)d_in[2];
    const float* Wr1  = (const float*)d_in[3];
    const float* b1   = (const float*)d_in[4];
    const float* ln_g = (const float*)d_in[5];
    const float* ln_b = (const float*)d_in[6];
    const float* Wres = (const float*)d_in[7];
    const float* bres = (const float*)d_in[8];
    const float* Wl2  = (const float*)d_in[9];
    const float* Wr2  = (const float*)d_in[10];
    const float* b2   = (const float*)d_in[11];
    const float* Wl3  = (const float*)d_in[12];
    const float* Wr3  = (const float*)d_in[13];
    const float* b3   = (const float*)d_in[14];
    const float* Wl4  = (const float*)d_in[15];
    const float* Wr4  = (const float*)d_in[16];
    const float* b4   = (const float*)d_in[17];
    float* out = (float*)d_out;

    char* w = (char*)d_ws;
    size_t off = 0;
    auto alloc = [&](size_t bytes) -> void* {
        off = (off + 255) & ~(size_t)255;
        void* pp = w + off;
        off += bytes;
        return pp;
    };

    int*   deg        = (int*)alloc(N_NODES * 4);
    int*   row_ptr    = (int*)alloc((N_NODES + 1) * 4);
    int*   bsum       = (int*)alloc(1024);
    int*   col        = (int*)alloc(N_EDGES * 4);
    int*   bh2        = (int*)alloc(BH2_N * 4);
    int*   bh         = (int*)alloc(64 * SORT_BLOCKS * 4);
    int*   ord        = (int*)alloc(N_NODES * 4);       // sorted slot -> original node
    unsigned short* Btw  = (unsigned short*)alloc(128 * 256 * 2);
    unsigned short* xcat = (unsigned short*)alloc((size_t)N_NODES * 128 * 2);  // [x | aggx] bf16
    unsigned short* hcat = (unsigned short*)alloc((size_t)N_NODES * 256 * 2);  // [h | aggh] bf16
    int*   packed  = (int*)alloc((size_t)N_EDGES * 4);   // CSR build scratch
    float* p       = (float*)alloc(N_NODES * 4);
    float* q       = (float*)alloc(N_NODES * 4);
    (void)ws_size; (void)n_in; (void)in_sizes; (void)out_size;

    const int NB = (N_NODES + 255) / 256;
    const int BHB = (BH2_N + 1023) / 1024;              // 184
    const int MB = (N_NODES + 127) / 128;               // 782

    // --- CSR build (original space): hist -> scan -> scatter -> build(deg+row_ptr+col); dsort -> ord ---
    bkt_hist_kernel<<<SCAT_BLOCKS, 256, 0, stream>>>(ei, bh2);
    gscan_a_kernel<<<BHB, 256, 0, stream>>>(bh2, bsum, BH2_N);
    scan_b_kernel<<<1, 256, 0, stream>>>(bsum, BHB);
    gscan_c_kernel<<<BHB, 256, 0, stream>>>(bh2, bsum, BH2_N);
    bkt_scatter2_kernel<<<SCAT_BLOCKS, 256, 0, stream>>>(ei, bh2, packed);
    bkt_build_kernel<<<NBKT, 256, 0, stream>>>(packed, bh2, deg, row_ptr, col);
    dsort_hist_kernel<<<SORT_BLOCKS, 256, 0, stream>>>(deg, bh);
    dsort_scan_kernel<<<1, 256, 0, stream>>>(bh);
    dsort_scat_kernel<<<SORT_BLOCKS, 256, 0, stream>>>(deg, bh, ord);

    // --- layer 1: xcat = [x | mean-agg(x)]; fused GEMM+LN -> hcat[:,0:128] ---
    xbf_kernel<<<(N_NODES * 16 + 255) / 256, 256, 0, stream>>>(x, xcat);
    agg64_kernel<<<(N_NODES + 15) / 16, 256, 0, stream>>>(xcat, row_ptr, col, ord);
    wprep1_kernel<<<128, 256, 0, stream>>>(Wr1, Wl1, Wres, Btw);
    mgemm1_ln_kernel<<<MB, 256, 0, stream>>>(xcat, Btw, N_NODES, b1, ln_g, ln_b, bres, hcat);

    // --- layer 2: agg(h) -> hcat[:,128:256]; GEMM [h|aggh] -> hcat[:,0:128] (bias+relu) ---
    agg128_kernel<<<(N_NODES + 7) / 8, 256, 0, stream>>>(hcat, row_ptr, col, ord);
    wprep23_kernel<<<128, 256, 0, stream>>>(Wl2, Wr2, Btw);
    mgemm_kernel<<<dim3(MB, 1), 256, 0, stream>>>(hcat, 256, Btw, N_NODES, b2, hcat, 256);

    // --- layer 3: agg(h) -> hcat[:,128:256]; fused GEMM+pq -> p, q (h3 never stored) ---
    agg128_kernel<<<(N_NODES + 7) / 8, 256, 0, stream>>>(hcat, row_ptr, col, ord);
    wprep23_kernel<<<128, 256, 0, stream>>>(Wl3, Wr3, Btw);
    mgemm_pq_kernel<<<MB, 256, 0, stream>>>(hcat, 256, Btw, N_NODES, b3, Wl4, Wr4, b4, p, q);

    // --- final ---
    final_kernel<<<NB, 256, 0, stream>>>(p, q, row_ptr, col, out);
}

// Round 15
// 419.382 us; speedup vs baseline: 1.1703x; 1.0452x over previous
//
#include <hip/hip_runtime.h>
#include <hip/hip_bf16.h>

#define N_NODES 100000
#define N_EDGES 1600000

#define NBKT 782                 // ceil(N_NODES / 128)
#define SCAT_BLOCKS 240
#define BKT_CHUNK 6667           // ceil(N_EDGES / 240)
#define LP 72                    // padded LDS row length in shorts (64 + 8)

#define SORT_BLOCKS 40
#define SORT_CHUNK 2500          // 40 * 2500 = 100000
#define BH2_N (NBKT * SCAT_BLOCKS)   // 187680
#define BHB ((BH2_N + 1023) / 1024)  // 184
#define XBF_BLOCKS 6250              // N_NODES*16/256

typedef __attribute__((ext_vector_type(8))) short short8v;
typedef __attribute__((ext_vector_type(4))) float float4v;

__device__ __forceinline__ unsigned short f2bf(float f) {
    unsigned int u = __float_as_uint(f);
    u = (u + 0x7FFFu + ((u >> 16) & 1u)) >> 16;   // RTNE
    return (unsigned short)u;
}
__device__ __forceinline__ float bf2f(unsigned short b) {
    return __uint_as_float((unsigned int)b << 16);
}

// ---------------- merged: bucket histogram (blocks 0..239) + x->bf16 (blocks 240..) ----------------
__global__ __launch_bounds__(256) void hist_xbf_kernel(const int* __restrict__ ei, int* __restrict__ bh2,
                                                       const float* __restrict__ x, unsigned short* __restrict__ xcat) {
    __shared__ int h[NBKT];
    int tid = threadIdx.x;
    if (blockIdx.x < SCAT_BLOCKS) {
        for (int i = tid; i < NBKT; i += 256) h[i] = 0;
        __syncthreads();
        int start = blockIdx.x * BKT_CHUNK;
        int end = start + BKT_CHUNK; if (end > N_EDGES) end = N_EDGES;
        for (int i = start + tid; i < end; i += 256) {
            int d = ei[N_EDGES + i];
            atomicAdd(&h[d >> 7], 1);
        }
        __syncthreads();
        for (int i = tid; i < NBKT; i += 256) bh2[i * SCAT_BLOCKS + blockIdx.x] = h[i];
    } else {
        int idx = (blockIdx.x - SCAT_BLOCKS) * 256 + tid;   // one float4 per thread
        if (idx < N_NODES * 16) {
            int node = idx >> 4;
            int f0 = (idx & 15) * 4;
            float4 v = *(const float4*)(x + (size_t)idx * 4);
            ushort4 o;
            o.x = f2bf(v.x); o.y = f2bf(v.y); o.z = f2bf(v.z); o.w = f2bf(v.w);
            *(ushort4*)(xcat + (size_t)node * 128 + f0) = o;
        }
    }
}

__global__ __launch_bounds__(256) void gscan_a_kernel(const int* __restrict__ in, int* __restrict__ bsum, int n) {
    __shared__ int lds[256];
    int tid = threadIdx.x;
    int base = blockIdx.x * 1024 + tid * 4;
    int s = 0;
    #pragma unroll
    for (int i = 0; i < 4; i++) s += (base + i < n) ? in[base + i] : 0;
    lds[tid] = s;
    __syncthreads();
    for (int off = 128; off; off >>= 1) {
        if (tid < off) lds[tid] += lds[tid + off];
        __syncthreads();
    }
    if (tid == 0) bsum[blockIdx.x] = lds[0];
}

// in-place exclusive scan apply; each block self-scans bsum (<=256 entries) in LDS
__global__ __launch_bounds__(256) void gscan_c_kernel(int* __restrict__ data, const int* __restrict__ bsum,
                                                      int nb, int n) {
    __shared__ int sb[256];
    __shared__ int lds[256];
    int tid = threadIdx.x;
    sb[tid] = (tid < nb) ? bsum[tid] : 0;
    __syncthreads();
    for (int off = 1; off < 256; off <<= 1) {
        int y = 0;
        if (tid >= off) y = sb[tid - off];
        __syncthreads();
        if (tid >= off) sb[tid] += y;
        __syncthreads();
    }
    int blockbase = (blockIdx.x == 0) ? 0 : sb[blockIdx.x - 1];

    int base = blockIdx.x * 1024 + tid * 4;
    int v[4];
    int s = 0;
    #pragma unroll
    for (int i = 0; i < 4; i++) {
        v[i] = (base + i < n) ? data[base + i] : 0;
        s += v[i];
    }
    lds[tid] = s;
    __syncthreads();
    for (int off = 1; off < 256; off <<= 1) {
        int y = 0;
        if (tid >= off) y = lds[tid - off];
        __syncthreads();
        if (tid >= off) lds[tid] += y;
        __syncthreads();
    }
    int run = blockbase + lds[tid] - s;
    #pragma unroll
    for (int i = 0; i < 4; i++) {
        if (base + i < n) data[base + i] = run;
        run += v[i];
    }
}

__global__ __launch_bounds__(256) void bkt_scatter2_kernel(const int* __restrict__ ei, const int* __restrict__ bh2,
                                                           int* __restrict__ packed) {
    __shared__ int h[NBKT];
    __shared__ int base[NBKT];
    int tid = threadIdx.x;
    for (int i = tid; i < NBKT; i += 256) { h[i] = 0; base[i] = bh2[i * SCAT_BLOCKS + blockIdx.x]; }
    __syncthreads();
    int start = blockIdx.x * BKT_CHUNK;
    int end = start + BKT_CHUNK; if (end > N_EDGES) end = N_EDGES;
    for (int i = start + tid; i < end; i += 256) {
        int s = ei[i];
        int d = ei[N_EDGES + i];
        int b = d >> 7;
        int pos = base[b] + atomicAdd(&h[b], 1);
        packed[pos] = (s << 7) | (d & 127);
    }
}

// merged: per-bucket degree count + LDS scan -> deg[], row_ptr[]; then fill col.
__global__ __launch_bounds__(256) void bkt_build_kernel(const int* __restrict__ packed, const int* __restrict__ bh2,
                                                        int* __restrict__ deg, int* __restrict__ row_ptr,
                                                        int* __restrict__ col) {
    __shared__ int c[128];
    __shared__ int rp[128];
    int tid = threadIdx.x;
    int s0 = bh2[blockIdx.x * SCAT_BLOCKS];
    int s1 = (blockIdx.x + 1 < NBKT) ? bh2[(blockIdx.x + 1) * SCAT_BLOCKS] : N_EDGES;
    if (tid < 128) c[tid] = 0;
    __syncthreads();
    for (int i = s0 + tid; i < s1; i += 256) atomicAdd(&c[packed[i] & 127], 1);
    __syncthreads();
    if (tid < 128) rp[tid] = c[tid];
    __syncthreads();
    for (int off = 1; off < 128; off <<= 1) {
        int y = 0;
        if (tid >= off && tid < 128) y = rp[tid - off];
        __syncthreads();
        if (tid >= off && tid < 128) rp[tid] += y;
        __syncthreads();
    }
    int node = blockIdx.x * 128 + tid;
    if (tid < 128) {
        rp[tid] = s0 + rp[tid] - c[tid];   // exclusive in-bucket prefix + bucket base
        if (node < N_NODES) {
            deg[node] = c[tid];
            row_ptr[node] = rp[tid];
        }
        c[tid] = 0;
    }
    if (blockIdx.x == 0 && tid == 0) row_ptr[N_NODES] = N_EDGES;
    __syncthreads();
    for (int i = s0 + tid; i < s1; i += 256) {
        int p = packed[i];
        int dl = p & 127;
        int pos = rp[dl] + atomicAdd(&c[dl], 1);
        col[pos] = p >> 7;
    }
}

// ---------------- degree counting sort -> ord[] ----------------
__global__ __launch_bounds__(256) void dsort_hist_kernel(const int* __restrict__ deg, int* __restrict__ bh) {
    __shared__ int h[64];
    int tid = threadIdx.x;
    if (tid < 64) h[tid] = 0;
    __syncthreads();
    int start = blockIdx.x * SORT_CHUNK;
    int end = start + SORT_CHUNK; if (end > N_NODES) end = N_NODES;
    for (int i = start + tid; i < end; i += 256) atomicAdd(&h[min(deg[i], 63)], 1);
    __syncthreads();
    if (tid < 64) bh[tid * SORT_BLOCKS + blockIdx.x] = h[tid];
}

// scatter; each block self-scans the full bh[2560] in LDS (exclusive prefix)
__global__ __launch_bounds__(256) void dsort_scat_kernel(const int* __restrict__ deg, const int* __restrict__ bh,
                                                         int* __restrict__ ord) {
    __shared__ int sbh[64 * SORT_BLOCKS];
    __shared__ int ps[256];
    __shared__ int h[64];
    int tid = threadIdx.x;
    int v[10];
    int s = 0;
    #pragma unroll
    for (int k = 0; k < 10; k++) { v[k] = bh[tid * 10 + k]; s += v[k]; }
    ps[tid] = s;
    if (tid < 64) h[tid] = 0;
    __syncthreads();
    for (int off = 1; off < 256; off <<= 1) {
        int y = 0;
        if (tid >= off) y = ps[tid - off];
        __syncthreads();
        if (tid >= off) ps[tid] += y;
        __syncthreads();
    }
    int run = ps[tid] - s;
    #pragma unroll
    for (int k = 0; k < 10; k++) { sbh[tid * 10 + k] = run; run += v[k]; }
    __syncthreads();
    int start = blockIdx.x * SORT_CHUNK;
    int end = start + SORT_CHUNK; if (end > N_NODES) end = N_NODES;
    for (int i = start + tid; i < end; i += 256) {
        int b = min(deg[i], 63);
        int pos = sbh[b * SORT_BLOCKS + blockIdx.x] + atomicAdd(&h[b], 1);
        ord[pos] = i;
    }
}

#define ACC4(u) { a0 += bf2f(u.x); a1 += bf2f(u.y); a2 += bf2f(u.z); a3 += bf2f(u.w); }

// ---------------- layer-1 agg: mean of xcat[j,0:64] -> xcat[i,64:128]; 16 lanes/node ----------------
__global__ __launch_bounds__(256) void agg64_kernel(unsigned short* __restrict__ xcat,
                                                    const int* __restrict__ row_ptr, const int* __restrict__ col,
                                                    const int* __restrict__ ord) {
    int tid = threadIdx.x;
    int slot = blockIdx.x * 16 + (tid >> 4);
    if (slot >= N_NODES) return;
    int i = ord[slot];
    int f0 = (tid & 15) * 4;
    int s = row_ptr[i], e = row_ptr[i + 1];
    float a0 = 0.f, a1 = 0.f, a2 = 0.f, a3 = 0.f;
    int t = s;
    while (t + 7 < e) {
        int j0 = col[t], j1 = col[t + 1], j2 = col[t + 2], j3 = col[t + 3];
        int j4 = col[t + 4], j5 = col[t + 5], j6 = col[t + 6], j7 = col[t + 7];
        ushort4 u0 = *(const ushort4*)(xcat + (size_t)j0 * 128 + f0);
        ushort4 u1 = *(const ushort4*)(xcat + (size_t)j1 * 128 + f0);
        ushort4 u2 = *(const ushort4*)(xcat + (size_t)j2 * 128 + f0);
        ushort4 u3 = *(const ushort4*)(xcat + (size_t)j3 * 128 + f0);
        ushort4 u4 = *(const ushort4*)(xcat + (size_t)j4 * 128 + f0);
        ushort4 u5 = *(const ushort4*)(xcat + (size_t)j5 * 128 + f0);
        ushort4 u6 = *(const ushort4*)(xcat + (size_t)j6 * 128 + f0);
        ushort4 u7 = *(const ushort4*)(xcat + (size_t)j7 * 128 + f0);
        ACC4(u0) ACC4(u1) ACC4(u2) ACC4(u3) ACC4(u4) ACC4(u5) ACC4(u6) ACC4(u7)
        t += 8;
    }
    if (t + 3 < e) {
        int j0 = col[t], j1 = col[t + 1], j2 = col[t + 2], j3 = col[t + 3];
        ushort4 u0 = *(const ushort4*)(xcat + (size_t)j0 * 128 + f0);
        ushort4 u1 = *(const ushort4*)(xcat + (size_t)j1 * 128 + f0);
        ushort4 u2 = *(const ushort4*)(xcat + (size_t)j2 * 128 + f0);
        ushort4 u3 = *(const ushort4*)(xcat + (size_t)j3 * 128 + f0);
        ACC4(u0) ACC4(u1) ACC4(u2) ACC4(u3)
        t += 4;
    }
    if (t + 1 < e) {
        int j0 = col[t], j1 = col[t + 1];
        ushort4 u0 = *(const ushort4*)(xcat + (size_t)j0 * 128 + f0);
        ushort4 u1 = *(const ushort4*)(xcat + (size_t)j1 * 128 + f0);
        ACC4(u0) ACC4(u1)
        t += 2;
    }
    if (t < e) {
        ushort4 u0 = *(const ushort4*)(xcat + (size_t)col[t] * 128 + f0);
        ACC4(u0)
    }
    float di = 1.0f / fmaxf((float)(e - s), 1.0f);
    ushort4 o;
    o.x = f2bf(a0 * di); o.y = f2bf(a1 * di); o.z = f2bf(a2 * di); o.w = f2bf(a3 * di);
    *(ushort4*)(xcat + (size_t)i * 128 + 64 + f0) = o;
}

// ---------------- layers 2/3 agg: mean of hcat[j,0:128] -> hcat[i,128:256]; 32 lanes/node ----------------
__global__ __launch_bounds__(256) void agg128_kernel(unsigned short* __restrict__ hcat,
                                                     const int* __restrict__ row_ptr, const int* __restrict__ col,
                                                     const int* __restrict__ ord) {
    int tid = threadIdx.x;
    int slot = blockIdx.x * 8 + (tid >> 5);
    if (slot >= N_NODES) return;
    int i = ord[slot];
    int f0 = (tid & 31) * 4;
    int s = row_ptr[i], e = row_ptr[i + 1];
    float a0 = 0.f, a1 = 0.f, a2 = 0.f, a3 = 0.f;
    int t = s;
    while (t + 7 < e) {
        int j0 = col[t], j1 = col[t + 1], j2 = col[t + 2], j3 = col[t + 3];
        int j4 = col[t + 4], j5 = col[t + 5], j6 = col[t + 6], j7 = col[t + 7];
        ushort4 u0 = *(const ushort4*)(hcat + (size_t)j0 * 256 + f0);
        ushort4 u1 = *(const ushort4*)(hcat + (size_t)j1 * 256 + f0);
        ushort4 u2 = *(const ushort4*)(hcat + (size_t)j2 * 256 + f0);
        ushort4 u3 = *(const ushort4*)(hcat + (size_t)j3 * 256 + f0);
        ushort4 u4 = *(const ushort4*)(hcat + (size_t)j4 * 256 + f0);
        ushort4 u5 = *(const ushort4*)(hcat + (size_t)j5 * 256 + f0);
        ushort4 u6 = *(const ushort4*)(hcat + (size_t)j6 * 256 + f0);
        ushort4 u7 = *(const ushort4*)(hcat + (size_t)j7 * 256 + f0);
        ACC4(u0) ACC4(u1) ACC4(u2) ACC4(u3) ACC4(u4) ACC4(u5) ACC4(u6) ACC4(u7)
        t += 8;
    }
    if (t + 3 < e) {
        int j0 = col[t], j1 = col[t + 1], j2 = col[t + 2], j3 = col[t + 3];
        ushort4 u0 = *(const ushort4*)(hcat + (size_t)j0 * 256 + f0);
        ushort4 u1 = *(const ushort4*)(hcat + (size_t)j1 * 256 + f0);
        ushort4 u2 = *(const ushort4*)(hcat + (size_t)j2 * 256 + f0);
        ushort4 u3 = *(const ushort4*)(hcat + (size_t)j3 * 256 + f0);
        ACC4(u0) ACC4(u1) ACC4(u2) ACC4(u3)
        t += 4;
    }
    if (t + 1 < e) {
        int j0 = col[t], j1 = col[t + 1];
        ushort4 u0 = *(const ushort4*)(hcat + (size_t)j0 * 256 + f0);
        ushort4 u1 = *(const ushort4*)(hcat + (size_t)j1 * 256 + f0);
        ACC4(u0) ACC4(u1)
        t += 2;
    }
    if (t < e) {
        ushort4 u0 = *(const ushort4*)(hcat + (size_t)col[t] * 256 + f0);
        ACC4(u0)
    }
    float di = 1.0f / fmaxf((float)(e - s), 1.0f);
    ushort4 o;
    o.x = f2bf(a0 * di); o.y = f2bf(a1 * di); o.z = f2bf(a2 * di); o.w = f2bf(a3 * di);
    *(ushort4*)(hcat + (size_t)i * 256 + 128 + f0) = o;
}

// ---------------- all weight preps in one launch (bf16 transposed) ----------------
// seg 0: Bt1[n*128+k], n in [0,256), k in [0,128)
// seg 1/2: Bt[n*256+k] for layers 2/3, n in [0,128), k in [0,256)
__global__ __launch_bounds__(256) void wprep_all_kernel(const float* __restrict__ Wr1, const float* __restrict__ Wl1,
                                                        const float* __restrict__ Wres,
                                                        const float* __restrict__ Wl2, const float* __restrict__ Wr2,
                                                        const float* __restrict__ Wl3, const float* __restrict__ Wr3,
                                                        unsigned short* __restrict__ Bt1,
                                                        unsigned short* __restrict__ Bt2,
                                                        unsigned short* __restrict__ Bt3) {
    int idx = blockIdx.x * 256 + threadIdx.x;
    int seg = idx >> 15;          // 32768 elements per segment
    int loc = idx & 32767;
    if (seg == 0) {
        int n = loc >> 7;
        int k = loc & 127;
        float v;
        if (n < 128) v = (k < 64) ? Wr1[k * 128 + n] : Wl1[(k - 64) * 128 + n];
        else         v = (k < 64) ? Wres[k * 128 + (n - 128)] : 0.f;
        Bt1[loc] = f2bf(v);
    } else if (seg == 1) {
        int n = loc >> 8;
        int k = loc & 255;
        float v = (k < 128) ? Wr2[k * 128 + n] : Wl2[(k - 128) * 128 + n];
        Bt2[loc] = f2bf(v);
    } else if (seg == 2) {
        int n = loc >> 8;
        int k = loc & 255;
        float v = (k < 128) ? Wr3[k * 128 + n] : Wl3[(k - 128) * 128 + n];
        Bt3[loc] = f2bf(v);
    }
}

// ---------------- layer-1 fused GEMM+LN ----------------
__global__ __launch_bounds__(256) void mgemm1_ln_kernel(const unsigned short* __restrict__ A,
                                                        const unsigned short* __restrict__ Bt, int M,
                                                        const float* __restrict__ b1, const float* __restrict__ ln_g,
                                                        const float* __restrict__ ln_b, const float* __restrict__ bres,
                                                        unsigned short* __restrict__ hcat) {
    __shared__ unsigned short As[128 * LP];
    __shared__ unsigned short Bs[256 * LP];
    __shared__ float lsum[2][128], lsq[2][128];
    int tid = threadIdx.x;
    int m0 = blockIdx.x * 128;

    int lane = tid & 63;
    int wave = tid >> 6;
    int wm = (wave & 1) * 64;
    int wn = (wave >> 1) * 64;
    int lm = lane & 15;
    int lk = (lane >> 4) * 8;

    float4v accT[4][4], accR[4][4];
    #pragma unroll
    for (int i = 0; i < 4; i++)
        #pragma unroll
        for (int j = 0; j < 4; j++) { accT[i][j] = (float4v)0.f; accR[i][j] = (float4v)0.f; }

    int sr = tid >> 3;
    int sc = (tid & 7) * 8;

    for (int ks = 0; ks < 128; ks += 64) {
        if (ks) __syncthreads();
        int kk = ks + sc;
        #pragma unroll
        for (int rr = 0; rr < 384; rr += 32) {
            int r = sr + rr;
            if (r < 128) {
                int gm = m0 + r; if (gm > M - 1) gm = M - 1;
                *(ulonglong2*)&As[r * LP + sc] = *(const ulonglong2*)(A + (size_t)gm * 128 + kk);
            } else {
                int br = r - 128;
                *(ulonglong2*)&Bs[br * LP + sc] = *(const ulonglong2*)(Bt + (size_t)br * 128 + kk);
            }
        }
        __syncthreads();

        #pragma unroll
        for (int k0 = 0; k0 < 64; k0 += 32) {
            short8v af[4], bfT[4], bfR[4];
            #pragma unroll
            for (int i = 0; i < 4; i++)
                af[i] = *(const short8v*)&As[(wm + i * 16 + lm) * LP + k0 + lk];
            #pragma unroll
            for (int j = 0; j < 4; j++) {
                bfT[j] = *(const short8v*)&Bs[(wn + j * 16 + lm) * LP + k0 + lk];
                bfR[j] = *(const short8v*)&Bs[(128 + wn + j * 16 + lm) * LP + k0 + lk];
            }
            #pragma unroll
            for (int i = 0; i < 4; i++)
                #pragma unroll
                for (int j = 0; j < 4; j++) {
                    accT[i][j] = __builtin_amdgcn_mfma_f32_16x16x32_bf16(af[i], bfT[j], accT[i][j], 0, 0, 0);
                    accR[i][j] = __builtin_amdgcn_mfma_f32_16x16x32_bf16(af[i], bfR[j], accR[i][j], 0, 0, 0);
                }
        }
    }

    int q = lane >> 4;
    int wnidx = wave >> 1;
    float b1v[4], gv[4], bbv[4], brv[4];
    #pragma unroll
    for (int j = 0; j < 4; j++) {
        int cc = wn + j * 16 + lm;
        b1v[j] = b1[cc]; gv[j] = ln_g[cc]; bbv[j] = ln_b[cc]; brv[j] = bres[cc];
    }
    #pragma unroll
    for (int i = 0; i < 4; i++) {
        #pragma unroll
        for (int r = 0; r < 4; r++) {
            float sp = 0.f, sq = 0.f;
            #pragma unroll
            for (int j = 0; j < 4; j++) {
                float tv = accT[i][j][r] + b1v[j];
                sp += tv; sq += tv * tv;
            }
            #pragma unroll
            for (int off = 1; off < 16; off <<= 1) {
                sp += __shfl_xor(sp, off);
                sq += __shfl_xor(sq, off);
            }
            if (lm == 0) {
                int m = wm + i * 16 + q * 4 + r;
                lsum[wnidx][m] = sp;
                lsq[wnidx][m] = sq;
            }
        }
    }
    __syncthreads();
    #pragma unroll
    for (int i = 0; i < 4; i++) {
        #pragma unroll
        for (int r = 0; r < 4; r++) {
            int m = wm + i * 16 + q * 4 + r;
            float sum = lsum[0][m] + lsum[1][m];
            float s2 = lsq[0][m] + lsq[1][m];
            float mu = sum * (1.f / 128.f);
            float var = s2 * (1.f / 128.f) - mu * mu;
            float rstd = rsqrtf(var + 1e-5f);
            int gm = m0 + m;
            if (gm < M) {
                #pragma unroll
                for (int j = 0; j < 4; j++) {
                    float tv = accT[i][j][r] + b1v[j];
                    float y = fmaxf((tv - mu) * rstd * gv[j] + bbv[j], 0.f) + accR[i][j][r] + brv[j];
                    hcat[(size_t)gm * 256 + wn + j * 16 + lm] = f2bf(y);
                }
            }
        }
    }
}

// ---------------- MFMA bf16 GEMM (layer 2): hcat[:,0:128] = relu(hcat@Bt^T + bias) ----------------
__global__ __launch_bounds__(256) void mgemm_kernel(const unsigned short* __restrict__ A, int lda,
                                                    const unsigned short* __restrict__ Bt, int M,
                                                    const float* __restrict__ bias,
                                                    unsigned short* __restrict__ C, int ldc) {
    __shared__ unsigned short As[128 * LP];
    __shared__ unsigned short Bs[128 * LP];
    int tid = threadIdx.x;
    int m0 = blockIdx.x * 128;
    int n0 = blockIdx.y * 128;

    int lane = tid & 63;
    int wave = tid >> 6;
    int wm = (wave & 1) * 64;
    int wn = (wave >> 1) * 64;
    int lm = lane & 15;
    int lk = (lane >> 4) * 8;

    float4v acc[4][4];
    #pragma unroll
    for (int i = 0; i < 4; i++)
        #pragma unroll
        for (int j = 0; j < 4; j++) acc[i][j] = (float4v)0.f;

    int sr = tid >> 3;
    int sc = (tid & 7) * 8;

    for (int ks = 0; ks < lda; ks += 64) {
        if (ks) __syncthreads();
        int kk = ks + sc;
        #pragma unroll
        for (int rr = 0; rr < 128; rr += 32) {
            int r = sr + rr;
            int gm = m0 + r; if (gm > M - 1) gm = M - 1;
            *(ulonglong2*)&As[r * LP + sc] = *(const ulonglong2*)(A + (size_t)gm * lda + kk);
            *(ulonglong2*)&Bs[r * LP + sc] = *(const ulonglong2*)(Bt + (size_t)(n0 + r) * lda + kk);
        }
        __syncthreads();

        #pragma unroll
        for (int k0 = 0; k0 < 64; k0 += 32) {
            short8v af[4], bf[4];
            #pragma unroll
            for (int i = 0; i < 4; i++)
                af[i] = *(const short8v*)&As[(wm + i * 16 + lm) * LP + k0 + lk];
            #pragma unroll
            for (int j = 0; j < 4; j++)
                bf[j] = *(const short8v*)&Bs[(wn + j * 16 + lm) * LP + k0 + lk];
            #pragma unroll
            for (int i = 0; i < 4; i++)
                #pragma unroll
                for (int j = 0; j < 4; j++)
                    acc[i][j] = __builtin_amdgcn_mfma_f32_16x16x32_bf16(af[i], bf[j], acc[i][j], 0, 0, 0);
        }
    }

    int r0b = (lane >> 4) * 4;
    #pragma unroll
    for (int i = 0; i < 4; i++) {
        #pragma unroll
        for (int j = 0; j < 4; j++) {
            int cc = n0 + wn + j * 16 + lm;
            float bv = (bias != nullptr) ? bias[cc] : 0.f;
            #pragma unroll
            for (int r = 0; r < 4; r++) {
                int m = m0 + wm + i * 16 + r0b + r;
                if (m < M) {
                    float v = acc[i][j][r];
                    if (bias != nullptr) v = fmaxf(v + bv, 0.f);
                    C[(size_t)m * ldc + cc] = f2bf(v);
                }
            }
        }
    }
}

// ---------------- layer-3 fused GEMM+pq ----------------
__global__ __launch_bounds__(256) void mgemm_pq_kernel(const unsigned short* __restrict__ A, int lda,
                                                       const unsigned short* __restrict__ Bt, int M,
                                                       const float* __restrict__ bias,
                                                       const float* __restrict__ Wl4, const float* __restrict__ Wr4,
                                                       const float* __restrict__ b4,
                                                       float* __restrict__ p, float* __restrict__ q) {
    __shared__ unsigned short As[128 * LP];
    __shared__ unsigned short Bs[128 * LP];
    __shared__ float psA[2][128], qsA[2][128];
    int tid = threadIdx.x;
    int m0 = blockIdx.x * 128;

    int lane = tid & 63;
    int wave = tid >> 6;
    int wm = (wave & 1) * 64;
    int wn = (wave >> 1) * 64;
    int lm = lane & 15;
    int lk = (lane >> 4) * 8;

    float4v acc[4][4];
    #pragma unroll
    for (int i = 0; i < 4; i++)
        #pragma unroll
        for (int j = 0; j < 4; j++) acc[i][j] = (float4v)0.f;

    int sr = tid >> 3;
    int sc = (tid & 7) * 8;

    for (int ks = 0; ks < lda; ks += 64) {
        if (ks) __syncthreads();
        int kk = ks + sc;
        #pragma unroll
        for (int rr = 0; rr < 128; rr += 32) {
            int r = sr + rr;
            int gm = m0 + r; if (gm > M - 1) gm = M - 1;
            *(ulonglong2*)&As[r * LP + sc] = *(const ulonglong2*)(A + (size_t)gm * lda + kk);
            *(ulonglong2*)&Bs[r * LP + sc] = *(const ulonglong2*)(Bt + (size_t)r * lda + kk);
        }
        __syncthreads();

        #pragma unroll
        for (int k0 = 0; k0 < 64; k0 += 32) {
            short8v af[4], bf[4];
            #pragma unroll
            for (int i = 0; i < 4; i++)
                af[i] = *(const short8v*)&As[(wm + i * 16 + lm) * LP + k0 + lk];
            #pragma unroll
            for (int j = 0; j < 4; j++)
                bf[j] = *(const short8v*)&Bs[(wn + j * 16 + lm) * LP + k0 + lk];
            #pragma unroll
            for (int i = 0; i < 4; i++)
                #pragma unroll
                for (int j = 0; j < 4; j++)
                    acc[i][j] = __builtin_amdgcn_mfma_f32_16x16x32_bf16(af[i], bf[j], acc[i][j], 0, 0, 0);
        }
    }

    int qd = lane >> 4;
    int wnidx = wave >> 1;
    float b3v[4], wlv[4], wrv[4];
    #pragma unroll
    for (int j = 0; j < 4; j++) {
        int cc = wn + j * 16 + lm;
        b3v[j] = bias[cc]; wlv[j] = Wl4[cc]; wrv[j] = Wr4[cc];
    }
    #pragma unroll
    for (int i = 0; i < 4; i++) {
        #pragma unroll
        for (int r = 0; r < 4; r++) {
            float pp = 0.f, qq = 0.f;
            #pragma unroll
            for (int j = 0; j < 4; j++) {
                float hv = fmaxf(acc[i][j][r] + b3v[j], 0.f);
                pp += hv * wlv[j]; qq += hv * wrv[j];
            }
            #pragma unroll
            for (int off = 1; off < 16; off <<= 1) {
                pp += __shfl_xor(pp, off);
                qq += __shfl_xor(qq, off);
            }
            if (lm == 0) {
                int m = wm + i * 16 + qd * 4 + r;
                psA[wnidx][m] = pp;
                qsA[wnidx][m] = qq;
            }
        }
    }
    __syncthreads();
    if (wnidx == 0 && lm == 0) {
        float b4v = b4[0];
        #pragma unroll
        for (int i = 0; i < 4; i++) {
            #pragma unroll
            for (int r = 0; r < 4; r++) {
                int m = wm + i * 16 + qd * 4 + r;
                int gm = m0 + m;
                if (gm < M) {
                    p[gm] = psA[0][m] + psA[1][m];
                    q[gm] = qsA[0][m] + qsA[1][m] + b4v;
                }
            }
        }
    }
}

__global__ __launch_bounds__(256) void final_kernel(const float* __restrict__ p, const float* __restrict__ q,
                                                    const int* __restrict__ row_ptr, const int* __restrict__ col,
                                                    float* __restrict__ out) {
    int i = blockIdx.x * 256 + threadIdx.x;   // original node id
    if (i >= N_NODES) return;
    int s = row_ptr[i], e = row_ptr[i + 1];
    float acc = 0.f;
    int t = s;
    for (; t + 3 < e; t += 4)
        acc += p[col[t]] + p[col[t + 1]] + p[col[t + 2]] + p[col[t + 3]];
    for (; t < e; t++) acc += p[col[t]];
    float di = 1.0f / fmaxf((float)(e - s), 1.0f);
    out[i] = acc * di + q[i];
}

// ---------------- launch ----------------

extern "C" void kernel_launch(void* const* d_in, const int* in_sizes, int n_in,
                              void* d_out, int out_size, void* d_ws, size_t ws_size,
                              hipStream_t stream) {
    const float* x    = (const float*)d_in[0];
    const int*   ei   = (const int*)d_in[1];
    const float* Wl1  = (const float*)d_in[2];
    const float* Wr1  = (const float*)d_in[3];
    const float* b1   = (const float*)d_in[4];
    const float* ln_g = (const float*)d_in[5];
    const float* ln_b = (const float*)d_in[6];
    const float* Wres = (const float*)d_in[7];
    const float* bres = (const float*)d_in[8];
    const float* Wl2  = (const float*)d_in[9];
    const float* Wr2  = (const float*)d_in[10];
    const float* b2   = (const float*)d_in[11];
    const float* Wl3  = (const float*)d_in[12];
    const float* Wr3  = (const float*)d_in[13];
    const float* b3   = (const float*)d_in[14];
    const float* Wl4  = (const float*)d_in[15];
    const float* Wr4  = (const float*)d_in[16];
    const float* b4   = (const float*)d_in[17];
    float* out = (float*)d_out;

    char* w = (char*)d_ws;
    size_t off = 0;
    auto alloc = [&](size_t bytes) -> void* {
        off = (off + 255) & ~(size_t)255;
        void* pp = w + off;
        off += bytes;
        return pp;
    };

    int*   deg        = (int*)alloc(N_NODES * 4);
    int*   row_ptr    = (int*)alloc((N_NODES + 1) * 4);
    int*   bsum       = (int*)alloc(1024);
    int*   col        = (int*)alloc(N_EDGES * 4);
    int*   bh2        = (int*)alloc(BH2_N * 4);
    int*   bh         = (int*)alloc(64 * SORT_BLOCKS * 4);
    int*   ord        = (int*)alloc(N_NODES * 4);       // sorted slot -> original node
    unsigned short* Bt1  = (unsigned short*)alloc(256 * 128 * 2);
    unsigned short* Bt2  = (unsigned short*)alloc(128 * 256 * 2);
    unsigned short* Bt3  = (unsigned short*)alloc(128 * 256 * 2);
    unsigned short* xcat = (unsigned short*)alloc((size_t)N_NODES * 128 * 2);  // [x | aggx] bf16
    unsigned short* hcat = (unsigned short*)alloc((size_t)N_NODES * 256 * 2);  // [h | aggh] bf16
    int*   packed  = (int*)alloc((size_t)N_EDGES * 4);   // CSR build scratch
    float* p       = (float*)alloc(N_NODES * 4);
    float* q       = (float*)alloc(N_NODES * 4);
    (void)ws_size; (void)n_in; (void)in_sizes; (void)out_size;

    const int NB = (N_NODES + 255) / 256;
    const int MB = (N_NODES + 127) / 128;               // 782

    // --- weight prep (independent, front-loaded) ---
    wprep_all_kernel<<<384, 256, 0, stream>>>(Wr1, Wl1, Wres, Wl2, Wr2, Wl3, Wr3, Bt1, Bt2, Bt3);

    // --- CSR build (original space) + x conversion overlapped ---
    hist_xbf_kernel<<<SCAT_BLOCKS + XBF_BLOCKS, 256, 0, stream>>>(ei, bh2, x, xcat);
    gscan_a_kernel<<<BHB, 256, 0, stream>>>(bh2, bsum, BH2_N);
    gscan_c_kernel<<<BHB, 256, 0, stream>>>(bh2, bsum, BHB, BH2_N);
    bkt_scatter2_kernel<<<SCAT_BLOCKS, 256, 0, stream>>>(ei, bh2, packed);
    bkt_build_kernel<<<NBKT, 256, 0, stream>>>(packed, bh2, deg, row_ptr, col);
    dsort_hist_kernel<<<SORT_BLOCKS, 256, 0, stream>>>(deg, bh);
    dsort_scat_kernel<<<SORT_BLOCKS, 256, 0, stream>>>(deg, bh, ord);

    // --- layer 1: agg(x) -> xcat[:,64:128]; fused GEMM+LN -> hcat[:,0:128] ---
    agg64_kernel<<<(N_NODES + 15) / 16, 256, 0, stream>>>(xcat, row_ptr, col, ord);
    mgemm1_ln_kernel<<<MB, 256, 0, stream>>>(xcat, Bt1, N_NODES, b1, ln_g, ln_b, bres, hcat);

    // --- layer 2: agg(h) -> hcat[:,128:256]; GEMM [h|aggh] -> hcat[:,0:128] (bias+relu) ---
    agg128_kernel<<<(N_NODES + 7) / 8, 256, 0, stream>>>(hcat, row_ptr, col, ord);
    mgemm_kernel<<<dim3(MB, 1), 256, 0, stream>>>(hcat, 256, Bt2, N_NODES, b2, hcat, 256);

    // --- layer 3: agg(h) -> hcat[:,128:256]; fused GEMM+pq -> p, q (h3 never stored) ---
    agg128_kernel<<<(N_NODES + 7) / 8, 256, 0, stream>>>(hcat, row_ptr, col, ord);
    mgemm_pq_kernel<<<MB, 256, 0, stream>>>(hcat, 256, Bt3, N_NODES, b3, Wl4, Wr4, b4, p, q);

    // --- final ---
    final_kernel<<<NB, 256, 0, stream>>>(p, q, row_ptr, col, out);
}